// Round 7
// baseline (1324.970 us; speedup 1.0000x reference)
//
#include <hip/hip_runtime.h>
#include <math.h>

#define T 65536
#define NCH 32
#define LCHUNK 512
#define CCHUNK 128
#define VH 8              // damping FIR taps (damp<=0.4: 0.4^8 ~ 6.5e-4)

// ws layout (float offsets).
#define OFS_A  0          // 32*65536: biquad out -> final pre-pan signal (in-place)
#define OFS_B1 2097152    // 32*65536: compressor target per sample
#define OFS_I  4194304    // 32*256*384: per-block group records (12 floats/group, 9 used)
#define OFS_P  7340032    // 32*64 derived params
#define OFS_M  7342080    // 32*144 chunk transition matrices
#define OFS_V  7346688    // 32*128*12 chunk zero-state finals
#define OFS_Z  7395840    // 32*128*12 chunk initial states

// ---------------- param kernel (also writes p_out) ----------------

__device__ void norm_store(double b0,double b1,double b2,double a0,double a1,double a2,
                           double* B, double* A1, double* A2, int k){
  B[k*3+0]=b0/a0; B[k*3+1]=b1/a0; B[k*3+2]=b2/a0; A1[k]=a1/a0; A2[k]=a2/a0;
}

__device__ void shelf_coefs(double fc, double g, double s, double* B, double* A1, double* A2, int k){
  double A  = pow(10.0, g/40.0);
  double w  = 2.0*3.14159265358979323846*fc/44100.0;
  double cw = cos(w);
  double al = sin(w)*0.70710678118654752;
  double sq = 2.0*sqrt(A)*al;
  double b0 = A*((A+1.0) + s*(A-1.0)*cw + sq);
  double b1 = -2.0*s*A*((A-1.0) + s*(A+1.0)*cw);
  double b2 = A*((A+1.0) + s*(A-1.0)*cw - sq);
  double a0 = (A+1.0) - s*(A-1.0)*cw + sq;
  double a1 = 2.0*s*((A-1.0) - s*(A+1.0)*cw);
  double a2 = (A+1.0) - s*(A-1.0)*cw - sq;
  norm_store(b0,b1,b2,a0,a1,a2,B,A1,A2,k);
}

__device__ void peak_coefs(double fc, double g, double q, double* B, double* A1, double* A2, int k){
  double A  = pow(10.0, g/40.0);
  double w  = 2.0*3.14159265358979323846*fc/44100.0;
  double cw = cos(w);
  double al = sin(w)/(2.0*q);
  norm_store(1.0+al*A, -2.0*cw, 1.0-al*A, 1.0+al/A, -2.0*cw, 1.0-al/A, B,A1,A2,k);
}

__global__ void k_params(const float* __restrict__ p, float* __restrict__ ws, float* __restrict__ pout){
  int ch = threadIdx.x;
  if (ch >= NCH) return;
  const float* pf = p + ch*24;
  float f[24];
  #pragma unroll
  for (int j=0;j<24;j++) f[j]=pf[j];

  double gain_in = (double)f[0]*60.0 - 48.0;
  double hp_fc  = (double)f[1]*350.0;
  double lp_fc  = (double)f[2]*19000.0 + 3000.0;
  double hs_fc  = (double)f[3]*14500.0 + 1500.0;
  double hs_g   = (double)f[4]*30.0 - 15.0;
  double ls_fc  = (double)f[5]*420.0 + 30.0;
  double ls_g   = (double)f[6]*30.0 - 15.0;
  double mh_fc  = (double)f[7]*6400.0 + 600.0;
  double mh_g   = (double)f[8]*30.0 - 15.0;
  double mh_q   = (double)f[9]*2.5 + 0.5;
  double ml_fc  = (double)f[10]*2300.0 + 200.0;
  double ml_g   = (double)f[11]*30.0 - 15.0;
  double ml_q   = (double)f[12]*2.5 + 0.5;
  double c_thr  = (double)f[13]*30.0 - 20.0;
  double c_rat  = (double)f[14]*19.0 + 1.0;
  double c_att  = (double)f[15]*29.0 + 1.0;
  double c_rel  = (double)f[16]*3900.0 + 100.0;
  double gain_out=(double)f[22]*60.0 - 48.0;
  double pan    = (double)f[23]*0.4 + 0.3;

  double B[18], A1[6], A2[6];
  { double K = tan(3.14159265358979323846*hp_fc/44100.0);
    double a1=(K-1.0)/(K+1.0), b0=1.0/(1.0+K);
    B[0]=b0; B[1]=-b0; B[2]=0.0; A1[0]=a1; A2[0]=0.0; }
  { double K = tan(3.14159265358979323846*lp_fc/44100.0);
    double a1=(K-1.0)/(K+1.0), b0=K/(1.0+K);
    B[3]=b0; B[4]=b0; B[5]=0.0; A1[1]=a1; A2[1]=0.0; }
  shelf_coefs(hs_fc, hs_g,  1.0, B, A1, A2, 2);
  shelf_coefs(ls_fc, ls_g, -1.0, B, A1, A2, 3);
  peak_coefs (mh_fc, mh_g, mh_q, B, A1, A2, 4);
  peak_coefs (ml_fc, ml_g, ml_q, B, A1, A2, 5);

  double gin = pow(10.0, gain_in/20.0);
  B[0]*=gin; B[1]*=gin; B[2]*=gin;  // fold input gain into section 0

  float* Pc = ws + OFS_P + ch*64;
  #pragma unroll
  for (int k=0;k<6;k++){
    Pc[k]    = (float)B[k*3+0];
    Pc[6+k]  = (float)B[k*3+1];
    Pc[12+k] = (float)B[k*3+2];
    Pc[18+k] = (float)A1[k];
    Pc[24+k] = (float)A2[k];
  }
  Pc[30] = (float)c_thr;
  Pc[31] = (float)(1.0 - 1.0/c_rat);
  Pc[32] = (float)exp(-1.0/(c_att*0.001*44100.0));
  Pc[33] = (float)exp(-1.0/(c_rel*0.001*44100.0));
  double fb   = (double)f[17]*0.28 + 0.7;
  double damp = (double)f[18]*0.4;
  double wet1 = 3.0*(double)f[19]*0.5*(1.0+(double)f[21]);
  double dryg = 2.0*(double)f[20];
  double gout = pow(10.0, gain_out/20.0);
  Pc[34] = (float)fb;
  Pc[35] = (float)damp;
  Pc[36] = (float)(wet1*gout);
  Pc[37] = (float)(dryg*gout/0.015);   // applied to xt (= comp*0.015)
  Pc[38] = (float)cos(pan*1.57079632679489662);
  Pc[39] = (float)sin(pan*1.57079632679489662);

  float* po = pout + ch*24;
  po[0]=(float)gain_in; po[1]=(float)hp_fc; po[2]=(float)lp_fc; po[3]=(float)hs_fc;
  po[4]=(float)hs_g; po[5]=(float)ls_fc; po[6]=(float)ls_g; po[7]=(float)mh_fc;
  po[8]=(float)mh_g; po[9]=(float)mh_q; po[10]=(float)ml_fc; po[11]=(float)ml_g;
  po[12]=(float)ml_q; po[13]=(float)c_thr; po[14]=(float)c_rat; po[15]=(float)c_att;
  po[16]=(float)c_rel; po[17]=f[17]; po[18]=f[18]; po[19]=f[19]; po[20]=f[20];
  po[21]=f[21]; po[22]=(float)gain_out; po[23]=(float)pan;
}

// ---------------- biquad cascade: chunked linear scan ----------------

__device__ __forceinline__ float bq_step(const float* b0, const float* b1, const float* b2,
                                         const float* a1, const float* a2,
                                         float* z1, float* z2, float s){
  #pragma unroll
  for (int k=0;k<6;k++){
    float y = fmaf(b0[k], s, z1[k]);
    z1[k] = fmaf(b1[k], s, fmaf(-a1[k], y, z2[k]));
    z2[k] = fmaf(b2[k], s, -a2[k]*y);
    s = y;
  }
  return s;
}

__device__ __forceinline__ void load_coefs(const float* Pc, float* b0, float* b1, float* b2,
                                           float* a1, float* a2){
  #pragma unroll
  for (int k=0;k<6;k++){
    b0[k]=Pc[k]; b1[k]=Pc[6+k]; b2[k]=Pc[12+k]; a1[k]=Pc[18+k]; a2[k]=Pc[24+k];
  }
}

__global__ __launch_bounds__(64,1) void k_chunk1(const float* __restrict__ x, float* __restrict__ ws){
  int tg = blockIdx.x*64 + threadIdx.x;      // 32 * 140 tasks
  int ch = tg / 140, sub = tg % 140;
  if (ch >= NCH) return;
  const float* Pc = ws + OFS_P + ch*64;
  float b0[6],b1[6],b2[6],a1[6],a2[6];
  load_coefs(Pc,b0,b1,b2,a1,a2);
  float z1[6]={0,0,0,0,0,0}, z2[6]={0,0,0,0,0,0};

  if (sub < CCHUNK){
    const float4* xp = (const float4*)(x + ch*T + sub*LCHUNK);
    for (int j=0;j<LCHUNK/4;j++){
      float4 v = xp[j];
      bq_step(b0,b1,b2,a1,a2,z1,z2,v.x);
      bq_step(b0,b1,b2,a1,a2,z1,z2,v.y);
      bq_step(b0,b1,b2,a1,a2,z1,z2,v.z);
      bq_step(b0,b1,b2,a1,a2,z1,z2,v.w);
    }
    float* vo = ws + OFS_V + (ch*CCHUNK + sub)*12;
    #pragma unroll
    for (int k=0;k<6;k++){ vo[2*k]=z1[k]; vo[2*k+1]=z2[k]; }
  } else {
    int j = sub - CCHUNK;                    // unit state index 0..11
    if ((j & 1)==0) z1[j>>1]=1.0f; else z2[j>>1]=1.0f;
    for (int t=0;t<LCHUNK;t++) bq_step(b0,b1,b2,a1,a2,z1,z2,0.0f);
    float* mo = ws + OFS_M + ch*144 + j*12;  // column j
    #pragma unroll
    for (int k=0;k<6;k++){ mo[2*k]=z1[k]; mo[2*k+1]=z2[k]; }
  }
}

__global__ __launch_bounds__(64,1) void k_chunk2(float* __restrict__ ws){
  int ch = threadIdx.x;
  if (ch >= NCH) return;
  const float* M = ws + OFS_M + ch*144;
  const float* V = ws + OFS_V + ch*CCHUNK*12;
  float*       Z = ws + OFS_Z + ch*CCHUNK*12;
  // hoist M into registers (aliasing with Z writes otherwise forces reloads)
  float Mr[144];
  #pragma unroll
  for (int i=0;i<144;i++) Mr[i]=M[i];
  float z[12], vbuf[12];
  #pragma unroll
  for (int i=0;i<12;i++) z[i]=0.0f;
  #pragma unroll
  for (int i=0;i<12;i++) vbuf[i]=V[i];
  for (int c=0;c<CCHUNK;c++){
    #pragma unroll
    for (int i=0;i<12;i++) Z[c*12+i]=z[i];
    float zn[12];
    #pragma unroll
    for (int i=0;i<12;i++) zn[i]=vbuf[i];
    if (c+1<CCHUNK){
      #pragma unroll
      for (int i=0;i<12;i++) vbuf[i]=V[(c+1)*12+i];
    }
    #pragma unroll
    for (int j=0;j<12;j++){
      float zj = z[j];
      #pragma unroll
      for (int i=0;i<12;i++) zn[i] = fmaf(Mr[j*12+i], zj, zn[i]);
    }
    #pragma unroll
    for (int i=0;i<12;i++) z[i]=zn[i];
  }
}

// pass 3: re-run chunks with correct init; write biquad out (A), target (B1),
// and per-8-group min-affine composed intercepts (12-float records, 9 used):
//   F_8(g) = min_{j=0..8}( aA^j aR^(8-j) g + beta_j )  -- EXACT
__global__ __launch_bounds__(64,1) void k_chunk3(const float* __restrict__ x, float* __restrict__ ws){
  int tg = blockIdx.x*64 + threadIdx.x;      // 4096
  int ch = tg >> 7, c = tg & (CCHUNK-1);
  const float* Pc = ws + OFS_P + ch*64;
  float b0[6],b1[6],b2[6],a1[6],a2[6];
  load_coefs(Pc,b0,b1,b2,a1,a2);
  float thr = Pc[30], rt = Pc[31];
  float aA = Pc[32], aR = Pc[33];
  float kA = 1.0f - aA, kR = 1.0f - aR;
  const float* Zi = ws + OFS_Z + (ch*CCHUNK + c)*12;
  float z1[6], z2[6];
  #pragma unroll
  for (int k=0;k<6;k++){ z1[k]=Zi[2*k]; z2[k]=Zi[2*k+1]; }
  const float4* xp = (const float4*)(x + ch*T + c*LCHUNK);
  float4* Ao  = (float4*)(ws + OFS_A  + (size_t)ch*T + c*LCHUNK);
  float4* B1o = (float4*)(ws + OFS_B1 + (size_t)ch*T + c*LCHUNK);
  float*  Ig  = ws + OFS_I + (size_t)ch*98304;

  for (int gg=0; gg<64; gg++){
    float4 v0 = xp[2*gg], v1 = xp[2*gg+1];
    float ya[8], Tv[8];
    ya[0]=bq_step(b0,b1,b2,a1,a2,z1,z2,v0.x);
    ya[1]=bq_step(b0,b1,b2,a1,a2,z1,z2,v0.y);
    ya[2]=bq_step(b0,b1,b2,a1,a2,z1,z2,v0.z);
    ya[3]=bq_step(b0,b1,b2,a1,a2,z1,z2,v0.w);
    ya[4]=bq_step(b0,b1,b2,a1,a2,z1,z2,v1.x);
    ya[5]=bq_step(b0,b1,b2,a1,a2,z1,z2,v1.y);
    ya[6]=bq_step(b0,b1,b2,a1,a2,z1,z2,v1.z);
    ya[7]=bq_step(b0,b1,b2,a1,a2,z1,z2,v1.w);
    #pragma unroll
    for (int s=0;s<8;s++)
      Tv[s] = fminf(0.0f, (thr - 6.0205999132796239f*log2f(fabsf(ya[s])+1e-6f))*rt);
    Ao[2*gg]   = make_float4(ya[0],ya[1],ya[2],ya[3]);
    Ao[2*gg+1] = make_float4(ya[4],ya[5],ya[6],ya[7]);
    B1o[2*gg]   = make_float4(Tv[0],Tv[1],Tv[2],Tv[3]);
    B1o[2*gg+1] = make_float4(Tv[4],Tv[5],Tv[6],Tv[7]);
    // DP: compose 8 min-affine steps; beta[j] = min intercept with j attack-steps
    float bb[9];
    bb[0] = kR*Tv[0]; bb[1] = kA*Tv[0];
    #pragma unroll
    for (int s=1;s<8;s++){
      float bA = kA*Tv[s], bR = kR*Tv[s];
      bb[s+1] = fmaf(aA, bb[s], bA);
      #pragma unroll
      for (int j=7;j>=1;j--){
        if (j<=s) bb[j] = fminf(fmaf(aA, bb[j-1], bA), fmaf(aR, bb[j], bR));
      }
      bb[0] = fmaf(aR, bb[0], bR);
    }
    int G = c*64 + gg;                         // global group index
    float* ig = Ig + (G>>5)*384 + (G&31)*12;   // block-major 12-float records
    *(float4*)(ig)   = make_float4(bb[0],bb[1],bb[2],bb[3]);
    *(float4*)(ig+4) = make_float4(bb[4],bb[5],bb[6],bb[7]);
    *(float4*)(ig+8) = make_float4(bb[8],0.0f,0.0f,0.0f);
  }
}

// ---------------- fused compressor-scan + freeverb --------------------------
// R16: SB=512 (128 iterations) to amortize the fixed per-iteration overhead
// (3 barriers + phase-entry latency) that R11-R15 showed is ~half the cost.
// 576 threads = 9 waves: 512 compute (1 sample each) + 64-lane scan wave.
// Allpass collision re-phasing (LA = 556,441,341,225 vs SB=512):
//   AP1 (556>=512): unique slots, read+write in B1 (all threads).
//   AP2 (441): t<441 in B1; t>=441 defer stage-2 to B2 (slot written by t-441
//     in B1, one barrier upstream; a-value in own registers).
//   AP3 (341): same split at 341 (B2 readers' slots written in B1).
//   AP4 (225): all stage-3 outputs -> aLds[512] (B1 for t<341, B2 for t>=341);
//     slot-owner t<225 runs the 2-3-sample chain + output stores in A(i+1)
//     (xfer trick generalized; 3 barriers downstream of every aLds write).
// Scan: 64 groups/block split 32 (B1) + 32 (B2) on lane 512.
// Comb gather at A(i) reads slots written >=4 blocks ago (L>=1116) -> no
// dependency on B1 comb writes of the previous iteration.
// Per-sample arithmetic identical to R10 (FIR order, AP fma sequence, gain
// recursion, scan operator) -> bit-identical results.

__global__ __launch_bounds__(576) void k_verb(float* __restrict__ ws){
  const int LC[8] = {1116,1188,1277,1356,1422,1491,1557,1617};
  const int COFF[8] = {0,1116,2304,3581,4937,6359,7850,9407};
  const int LA[4] = {556,441,341,225};
  const int AOFF[4] = {0,556,997,1338};
  const int SBV = 512, NBLKV = 128;
  extern __shared__ float smem[];
  float* cb    = smem;            // 11024
  float* ab    = smem + 11024;    // 1563 (pad to 12588)
  float* cHf   = smem + 12588;    // 8 x 520  [k][8 halo + 512]
  float* xtsD  = smem + 16748;    // 2 x 512 (dbuf: outputs consumed in A(i+1))
  float* aLds  = smem + 17772;    // 512 stage-3 outputs
  float* B1stD = smem + 18284;    // 2 x 512 target staging
  float* IldS  = smem + 19308;    // 64 group records x 12
  float* gBD   = smem + 20076;    // 2 x 64 group-boundary g
  // total 20204 floats = 80816 B (dynamic LDS)
  int ch = blockIdx.x, tid = threadIdx.x;
  const float* Pc = ws + OFS_P + ch*64;
  float fb = Pc[34], damp = Pc[35], wet1 = Pc[36], dryk = Pc[37];
  float aA = Pc[32], aR = Pc[33];
  float kA = 1.0f - aA, kR = 1.0f - aR;
  float omd = 1.0f - damp;
  float* Aio = ws + OFS_A + (size_t)ch*T;
  const float* B1c = ws + OFS_B1 + (size_t)ch*T;
  const float* IG  = ws + OFS_I + (size_t)ch*98304;
  for (int i=tid;i<16748;i+=576) smem[i]=0.0f;   // cb, ab, cH (incl. halos)
  bool scanw = (tid >= 512);
  int sl = tid - 512;
  // FIR weights damp^d
  float w[VH];
  { float pw = 1.0f;
    #pragma unroll
    for (int d=0;d<VH;d++){ w[d]=pw; pw*=damp; } }
  // scan slopes s_j = aA^j aR^(8-j)
  float sj[9];
  { float pA = 1.0f;
    #pragma unroll
    for (int j=0;j<9;j++){ sj[j]=pA; pA*=aA; }
    float pR = 1.0f;
    #pragma unroll
    for (int j=8;j>=0;j--){ sj[j]*=pR; pR*=aR; } }
  int cbb[8] = {0,0,0,0,0,0,0,0};
  int abb[4] = {0,0,0,0};
  int ab4p = 0;                    // AP4 base of the PREVIOUS block
  float gcarry = 0.0f;
  float4 iR0, iR1, iR2, bR0, bR1;
  float xv = 0.0f;

  // ---- prologue: IldS=I(0); B1st[0]=t(0), B1st[1]=t(1); regs=I(1); xv=x(0) ----
  if (scanw){
    const float4* isrc = (const float4*)(IG);
    float4* idst = (float4*)IldS;
    idst[sl]     = isrc[sl];
    idst[64+sl]  = isrc[64+sl];
    idst[128+sl] = isrc[128+sl];
    const float4* i1 = (const float4*)(IG + 768);
    iR0 = i1[sl]; iR1 = i1[64+sl]; iR2 = i1[128+sl];
    const float4* bsrc = (const float4*)(B1c);
    ((float4*)B1stD)[sl]        = bsrc[sl];
    ((float4*)B1stD)[64+sl]     = bsrc[64+sl];
    ((float4*)(B1stD+512))[sl]    = bsrc[128+sl];
    ((float4*)(B1stD+512))[64+sl] = bsrc[192+sl];
  } else {
    xv = Aio[tid];
  }
  __syncthreads();
  if (tid == 512){
    float g = 0.0f;
    for (int m=0;m<64;m++){
      gBD[m] = g;
      const float* Ip = &IldS[m*12];
      float f0=fmaf(sj[0],g,Ip[0]), f1=fmaf(sj[1],g,Ip[1]), f2=fmaf(sj[2],g,Ip[2]);
      float f3=fmaf(sj[3],g,Ip[3]), f4=fmaf(sj[4],g,Ip[4]), f5=fmaf(sj[5],g,Ip[5]);
      float f6=fmaf(sj[6],g,Ip[6]), f7=fmaf(sj[7],g,Ip[7]), f8=fmaf(sj[8],g,Ip[8]);
      g = fminf(fminf(fminf(f0,f1),fminf(f2,f3)),
                fminf(fminf(f4,f5),fminf(fminf(f6,f7),f8)));
    }
    gcarry = g;
  }
  __syncthreads();

  for (int i=0;i<NBLKV;i++){
    int t0 = i<<9;
    int p = i & 1;
    float xt = 0.0f, acc = 0.0f, a = 0.0f;
    // ---------- phase A ----------
    if (tid < 512){
      // finish previous block: AP4 chain per slot-owner + output stores
      if (i > 0 && tid < 225){
        const float* xtsP = xtsD + (p^1)*512;
        int slot = ab4p + tid; if (slot >= 225) slot -= 225;
        float bv  = ab[AOFF[3]+slot];
        float a0  = aLds[tid];
        float y0  = bv - a0;
        float v1  = fmaf(0.5f, bv, a0);
        Aio[t0-512+tid] = fmaf(y0, wet1, xtsP[tid]*dryk);
        float a1v = aLds[225+tid];
        float y1  = v1 - a1v;
        float v2  = fmaf(0.5f, v1, a1v);
        Aio[t0-512+225+tid] = fmaf(y1, wet1, xtsP[225+tid]*dryk);
        float vf = v2;
        if (tid < 62){
          float a2v = aLds[450+tid];
          float y2  = v2 - a2v;
          vf = fmaf(0.5f, v2, a2v);
          Aio[t0-512+450+tid] = fmaf(y2, wet1, xtsP[450+tid]*dryk);
        }
        ab[AOFF[3]+slot] = vf;
      }
      // gain recovery (8-sample groups, identical math to R10)
      int m = tid>>3, r = tid&7;
      float g = gBD[p*64+m];
      const float* Bl = B1stD + p*512 + (m<<3);
      float4 q0 = *(const float4*)(Bl);
      float4 q1 = *(const float4*)(Bl+4);
      float tv[8] = {q0.x,q0.y,q0.z,q0.w,q1.x,q1.y,q1.z,q1.w};
      #pragma unroll
      for (int s=0;s<8;s++){
        if (s<=r){
          float tt = tv[s];
          g = fminf(fmaf(aA,g,kA*tt), fmaf(aR,g,kR*tt));
        }
      }
      xt = xv * exp2f(g*0.16609640474436813f) * 0.015f;
      xtsD[p*512+tid] = xt;
      // comb gather (slots written >=4 blocks ago)
      #pragma unroll
      for (int k=0;k<8;k++){
        int idx = cbb[k]+tid; if (idx>=LC[k]) idx-=LC[k];
        float o = cb[COFF[k]+idx];
        cHf[k*520+VH+tid] = omd*o;
        acc += o;
      }
    } else if (i+1 < NBLKV){
      // scan wave: stage IldS = I(i+1); B1st[(i+1)&1] = t(i+1)
      float4* idst = (float4*)IldS;
      idst[sl]     = iR0;
      idst[64+sl]  = iR1;
      idst[128+sl] = iR2;
      if (i >= 1){
        float4* bdst = (float4*)(B1stD + ((i+1)&1)*512);
        bdst[sl]    = bR0;
        bdst[64+sl] = bR1;
      }
    }
    __syncthreads();
    // ---------- phase B1 ----------
    if (tid < 512){
      if (i+1 < NBLKV) xv = Aio[t0+512+tid];   // prefetch next x
      // FIR damping + comb writes
      #pragma unroll
      for (int k=0;k<8;k++){
        float s = 0.0f;
        #pragma unroll
        for (int d=0;d<VH;d++) s = fmaf(w[d], cHf[k*520+VH+tid-d], s);
        int idx = cbb[k]+tid; if (idx>=LC[k]) idx-=LC[k];
        cb[COFF[k]+idx] = fmaf(fb, s, xt);
      }
      a = acc;
      // AP1 (556 >= 512): all threads
      { int idx = abb[0]+tid;
        if (idx>=LA[0]) idx-=LA[0]; if (idx>=LA[0]) idx-=LA[0]; if (idx>=LA[0]) idx-=LA[0];
        float bv = ab[AOFF[0]+idx];
        ab[AOFF[0]+idx] = fmaf(0.5f, bv, a);
        a = bv - a; }
      // AP2 (441): t<441 here; t>=441 deferred to B2
      if (tid < 441){
        int idx = abb[1]+tid;
        if (idx>=LA[1]) idx-=LA[1]; if (idx>=LA[1]) idx-=LA[1]; if (idx>=LA[1]) idx-=LA[1];
        float bv = ab[AOFF[1]+idx];
        ab[AOFF[1]+idx] = fmaf(0.5f, bv, a);
        a = bv - a;
      }
      // AP3 (341): t<341 here; t>=341 deferred to B2
      if (tid < 341){
        int idx = abb[2]+tid;
        if (idx>=LA[2]) idx-=LA[2]; if (idx>=LA[2]) idx-=LA[2]; if (idx>=LA[2]) idx-=LA[2];
        float bv = ab[AOFF[2]+idx];
        ab[AOFF[2]+idx] = fmaf(0.5f, bv, a);
        a = bv - a;
        aLds[tid] = a;                         // stage-3 output for AP4 owners
      }
    } else {
      if (i+2 < NBLKV){                        // stage block i+2 into regs
        const float4* isrc = (const float4*)(IG + (size_t)(i+2)*768);
        iR0 = isrc[sl]; iR1 = isrc[64+sl]; iR2 = isrc[128+sl];
        const float4* bsrc = (const float4*)(B1c + (size_t)(i+2)*SBV);
        bR0 = bsrc[sl]; bR1 = bsrc[64+sl];
      }
      if (tid == 512 && i+1 < NBLKV){          // scan groups 0-31 of block i+1
        int q = (i+1)&1;
        float g = gcarry;
        #pragma unroll 4
        for (int m=0;m<32;m++){
          gBD[q*64+m] = g;
          const float* Ip = &IldS[m*12];
          float f0=fmaf(sj[0],g,Ip[0]), f1=fmaf(sj[1],g,Ip[1]), f2=fmaf(sj[2],g,Ip[2]);
          float f3=fmaf(sj[3],g,Ip[3]), f4=fmaf(sj[4],g,Ip[4]), f5=fmaf(sj[5],g,Ip[5]);
          float f6=fmaf(sj[6],g,Ip[6]), f7=fmaf(sj[7],g,Ip[7]), f8=fmaf(sj[8],g,Ip[8]);
          g = fminf(fminf(fminf(f0,f1),fminf(f2,f3)),
                    fminf(fminf(f4,f5),fminf(fminf(f6,f7),f8)));
        }
        gcarry = g;
      }
    }
    __syncthreads();
    // ---------- phase B2 ----------
    if (tid < 512){
      if (tid >= 441){                         // deferred AP2 stage
        int idx = abb[1]+tid;
        if (idx>=LA[1]) idx-=LA[1]; if (idx>=LA[1]) idx-=LA[1]; if (idx>=LA[1]) idx-=LA[1];
        float bv = ab[AOFF[1]+idx];            // written by tid-441 in B1
        ab[AOFF[1]+idx] = fmaf(0.5f, bv, a);
        a = bv - a;
      }
      if (tid >= 341){                         // deferred AP3 stage
        int idx = abb[2]+tid;
        if (idx>=LA[2]) idx-=LA[2]; if (idx>=LA[2]) idx-=LA[2]; if (idx>=LA[2]) idx-=LA[2];
        float bv = ab[AOFF[2]+idx];            // written by tid-341 in B1
        ab[AOFF[2]+idx] = fmaf(0.5f, bv, a);
        a = bv - a;
        aLds[tid] = a;
      }
      if (tid < 56){                           // halo: block samples 505..511
        int k = tid/7, d = tid%7;
        cHf[k*520+1+d] = cHf[k*520+513+d];
      }
    } else {
      if (tid == 512 && i+1 < NBLKV){          // scan groups 32-63 of block i+1
        int q = (i+1)&1;
        float g = gcarry;
        #pragma unroll 4
        for (int m=32;m<64;m++){
          gBD[q*64+m] = g;
          const float* Ip = &IldS[m*12];
          float f0=fmaf(sj[0],g,Ip[0]), f1=fmaf(sj[1],g,Ip[1]), f2=fmaf(sj[2],g,Ip[2]);
          float f3=fmaf(sj[3],g,Ip[3]), f4=fmaf(sj[4],g,Ip[4]), f5=fmaf(sj[5],g,Ip[5]);
          float f6=fmaf(sj[6],g,Ip[6]), f7=fmaf(sj[7],g,Ip[7]), f8=fmaf(sj[8],g,Ip[8]);
          g = fminf(fminf(fminf(f0,f1),fminf(f2,f3)),
                    fminf(fminf(f4,f5),fminf(fminf(f6,f7),f8)));
        }
        gcarry = g;
      }
    }
    // advance delay bases (snapshot AP4 base for the deferred chain in A(i+1))
    ab4p = abb[3];
    #pragma unroll
    for (int k=0;k<8;k++){ cbb[k]+=SBV; if (cbb[k]>=LC[k]) cbb[k]-=LC[k]; }
    #pragma unroll
    for (int j=0;j<4;j++){
      abb[j]+=SBV;
      if (abb[j]>=LA[j]) abb[j]-=LA[j];
      if (abb[j]>=LA[j]) abb[j]-=LA[j];
      if (abb[j]>=LA[j]) abb[j]-=LA[j];
    }
    __syncthreads();
  }
  // epilogue: AP4 chain + outputs of the last block
  if (tid < 225){
    int t0e = (NBLKV-1)<<9;
    const float* xtsP = xtsD + ((NBLKV-1)&1)*512;
    int slot = ab4p + tid; if (slot >= 225) slot -= 225;
    float bv  = ab[AOFF[3]+slot];
    float a0  = aLds[tid];
    float v1  = fmaf(0.5f, bv, a0);
    Aio[t0e+tid] = fmaf(bv - a0, wet1, xtsP[tid]*dryk);
    float a1v = aLds[225+tid];
    float v2  = fmaf(0.5f, v1, a1v);
    Aio[t0e+225+tid] = fmaf(v1 - a1v, wet1, xtsP[225+tid]*dryk);
    if (tid < 62){
      float a2v = aLds[450+tid];
      Aio[t0e+450+tid] = fmaf(v2 - a2v, wet1, xtsP[450+tid]*dryk);
    }
  }
}

// ---------------- pan mix ----------------

__global__ void k_mix(const float* __restrict__ ws, float* __restrict__ out){
  int id = blockIdx.x*256 + threadIdx.x;   // 4*65536
  int t = id & (T-1), b = id >> 16;
  const float* Av = ws + OFS_A + (size_t)b*8*T + t;
  const float* P = ws + OFS_P;
  float s0=0.0f, s1=0.0f;
  #pragma unroll
  for (int n=0;n<8;n++){
    float v = Av[(size_t)n*T];
    int ch = b*8+n;
    s0 = fmaf(v, P[ch*64+38], s0);
    s1 = fmaf(v, P[ch*64+39], s1);
  }
  out[b*2*T + t]     = s0;
  out[b*2*T + T + t] = s1;
}

extern "C" void kernel_launch(void* const* d_in, const int* in_sizes, int n_in,
                              void* d_out, int out_size, void* d_ws, size_t ws_size,
                              hipStream_t stream) {
  const float* x = (const float*)d_in[0];
  const float* p = (const float*)d_in[1];
  float* out = (float*)d_out;
  float* ws  = (float*)d_ws;

  // opt-in to >64KB dynamic LDS for k_verb (host-side attribute, capture-safe)
  (void)hipFuncSetAttribute((const void*)k_verb,
                            hipFuncAttributeMaxDynamicSharedMemorySize, 131072);

  k_params<<<1, 64, 0, stream>>>(p, ws, out + 4*2*T);
  k_chunk1<<<70, 64, 0, stream>>>(x, ws);
  k_chunk2<<<1, 64, 0, stream>>>(ws);
  k_chunk3<<<64, 64, 0, stream>>>(x, ws);
  k_verb  <<<NCH, 576, 20204*4, stream>>>(ws);
  k_mix   <<<(4*T)/256, 256, 0, stream>>>(ws, out);
}

// Round 8
// 899.484 us; speedup vs baseline: 1.4730x; 1.4730x over previous
//
#include <hip/hip_runtime.h>
#include <math.h>

#define T 65536
#define NCH 32
#define LCHUNK 512
#define CCHUNK 128
#define SB 256            // reverb block length (65536 = 256 blocks of 256)
#define NBLK 256
#define VH 8              // damping FIR taps (damp<=0.4: 0.4^8 ~ 6.5e-4)

// ws layout (float offsets).
#define OFS_A  0          // 32*65536: biquad out -> final pre-pan signal (in-place)
#define OFS_B1 2097152    // 32*65536: compressor target per sample
#define OFS_I  4194304    // 32*256*384: per-block group records (12 floats/group, 9 used)
#define OFS_P  7340032    // 32*64 derived params
#define OFS_M  7342080    // 32*144 chunk transition matrices
#define OFS_V  7346688    // 32*128*12 chunk zero-state finals
#define OFS_Z  7395840    // 32*128*12 chunk initial states

// ---------------- param kernel (also writes p_out) ----------------

__device__ void norm_store(double b0,double b1,double b2,double a0,double a1,double a2,
                           double* B, double* A1, double* A2, int k){
  B[k*3+0]=b0/a0; B[k*3+1]=b1/a0; B[k*3+2]=b2/a0; A1[k]=a1/a0; A2[k]=a2/a0;
}

__device__ void shelf_coefs(double fc, double g, double s, double* B, double* A1, double* A2, int k){
  double A  = pow(10.0, g/40.0);
  double w  = 2.0*3.14159265358979323846*fc/44100.0;
  double cw = cos(w);
  double al = sin(w)*0.70710678118654752;
  double sq = 2.0*sqrt(A)*al;
  double b0 = A*((A+1.0) + s*(A-1.0)*cw + sq);
  double b1 = -2.0*s*A*((A-1.0) + s*(A+1.0)*cw);
  double b2 = A*((A+1.0) + s*(A-1.0)*cw - sq);
  double a0 = (A+1.0) - s*(A-1.0)*cw + sq;
  double a1 = 2.0*s*((A-1.0) - s*(A+1.0)*cw);
  double a2 = (A+1.0) - s*(A-1.0)*cw - sq;
  norm_store(b0,b1,b2,a0,a1,a2,B,A1,A2,k);
}

__device__ void peak_coefs(double fc, double g, double q, double* B, double* A1, double* A2, int k){
  double A  = pow(10.0, g/40.0);
  double w  = 2.0*3.14159265358979323846*fc/44100.0;
  double cw = cos(w);
  double al = sin(w)/(2.0*q);
  norm_store(1.0+al*A, -2.0*cw, 1.0-al*A, 1.0+al/A, -2.0*cw, 1.0-al/A, B,A1,A2,k);
}

__global__ void k_params(const float* __restrict__ p, float* __restrict__ ws, float* __restrict__ pout){
  int ch = threadIdx.x;
  if (ch >= NCH) return;
  const float* pf = p + ch*24;
  float f[24];
  #pragma unroll
  for (int j=0;j<24;j++) f[j]=pf[j];

  double gain_in = (double)f[0]*60.0 - 48.0;
  double hp_fc  = (double)f[1]*350.0;
  double lp_fc  = (double)f[2]*19000.0 + 3000.0;
  double hs_fc  = (double)f[3]*14500.0 + 1500.0;
  double hs_g   = (double)f[4]*30.0 - 15.0;
  double ls_fc  = (double)f[5]*420.0 + 30.0;
  double ls_g   = (double)f[6]*30.0 - 15.0;
  double mh_fc  = (double)f[7]*6400.0 + 600.0;
  double mh_g   = (double)f[8]*30.0 - 15.0;
  double mh_q   = (double)f[9]*2.5 + 0.5;
  double ml_fc  = (double)f[10]*2300.0 + 200.0;
  double ml_g   = (double)f[11]*30.0 - 15.0;
  double ml_q   = (double)f[12]*2.5 + 0.5;
  double c_thr  = (double)f[13]*30.0 - 20.0;
  double c_rat  = (double)f[14]*19.0 + 1.0;
  double c_att  = (double)f[15]*29.0 + 1.0;
  double c_rel  = (double)f[16]*3900.0 + 100.0;
  double gain_out=(double)f[22]*60.0 - 48.0;
  double pan    = (double)f[23]*0.4 + 0.3;

  double B[18], A1[6], A2[6];
  { double K = tan(3.14159265358979323846*hp_fc/44100.0);
    double a1=(K-1.0)/(K+1.0), b0=1.0/(1.0+K);
    B[0]=b0; B[1]=-b0; B[2]=0.0; A1[0]=a1; A2[0]=0.0; }
  { double K = tan(3.14159265358979323846*lp_fc/44100.0);
    double a1=(K-1.0)/(K+1.0), b0=K/(1.0+K);
    B[3]=b0; B[4]=b0; B[5]=0.0; A1[1]=a1; A2[1]=0.0; }
  shelf_coefs(hs_fc, hs_g,  1.0, B, A1, A2, 2);
  shelf_coefs(ls_fc, ls_g, -1.0, B, A1, A2, 3);
  peak_coefs (mh_fc, mh_g, mh_q, B, A1, A2, 4);
  peak_coefs (ml_fc, ml_g, ml_q, B, A1, A2, 5);

  double gin = pow(10.0, gain_in/20.0);
  B[0]*=gin; B[1]*=gin; B[2]*=gin;  // fold input gain into section 0

  float* Pc = ws + OFS_P + ch*64;
  #pragma unroll
  for (int k=0;k<6;k++){
    Pc[k]    = (float)B[k*3+0];
    Pc[6+k]  = (float)B[k*3+1];
    Pc[12+k] = (float)B[k*3+2];
    Pc[18+k] = (float)A1[k];
    Pc[24+k] = (float)A2[k];
  }
  Pc[30] = (float)c_thr;
  Pc[31] = (float)(1.0 - 1.0/c_rat);
  Pc[32] = (float)exp(-1.0/(c_att*0.001*44100.0));
  Pc[33] = (float)exp(-1.0/(c_rel*0.001*44100.0));
  double fb   = (double)f[17]*0.28 + 0.7;
  double damp = (double)f[18]*0.4;
  double wet1 = 3.0*(double)f[19]*0.5*(1.0+(double)f[21]);
  double dryg = 2.0*(double)f[20];
  double gout = pow(10.0, gain_out/20.0);
  Pc[34] = (float)fb;
  Pc[35] = (float)damp;
  Pc[36] = (float)(wet1*gout);
  Pc[37] = (float)(dryg*gout/0.015);   // applied to xt (= comp*0.015)
  Pc[38] = (float)cos(pan*1.57079632679489662);
  Pc[39] = (float)sin(pan*1.57079632679489662);

  float* po = pout + ch*24;
  po[0]=(float)gain_in; po[1]=(float)hp_fc; po[2]=(float)lp_fc; po[3]=(float)hs_fc;
  po[4]=(float)hs_g; po[5]=(float)ls_fc; po[6]=(float)ls_g; po[7]=(float)mh_fc;
  po[8]=(float)mh_g; po[9]=(float)mh_q; po[10]=(float)ml_fc; po[11]=(float)ml_g;
  po[12]=(float)ml_q; po[13]=(float)c_thr; po[14]=(float)c_rat; po[15]=(float)c_att;
  po[16]=(float)c_rel; po[17]=f[17]; po[18]=f[18]; po[19]=f[19]; po[20]=f[20];
  po[21]=f[21]; po[22]=(float)gain_out; po[23]=(float)pan;
}

// ---------------- biquad cascade: chunked linear scan ----------------

__device__ __forceinline__ float bq_step(const float* b0, const float* b1, const float* b2,
                                         const float* a1, const float* a2,
                                         float* z1, float* z2, float s){
  #pragma unroll
  for (int k=0;k<6;k++){
    float y = fmaf(b0[k], s, z1[k]);
    z1[k] = fmaf(b1[k], s, fmaf(-a1[k], y, z2[k]));
    z2[k] = fmaf(b2[k], s, -a2[k]*y);
    s = y;
  }
  return s;
}

__device__ __forceinline__ void load_coefs(const float* Pc, float* b0, float* b1, float* b2,
                                           float* a1, float* a2){
  #pragma unroll
  for (int k=0;k<6;k++){
    b0[k]=Pc[k]; b1[k]=Pc[6+k]; b2[k]=Pc[12+k]; a1[k]=Pc[18+k]; a2[k]=Pc[24+k];
  }
}

__global__ __launch_bounds__(64,1) void k_chunk1(const float* __restrict__ x, float* __restrict__ ws){
  int tg = blockIdx.x*64 + threadIdx.x;      // 32 * 140 tasks
  int ch = tg / 140, sub = tg % 140;
  if (ch >= NCH) return;
  const float* Pc = ws + OFS_P + ch*64;
  float b0[6],b1[6],b2[6],a1[6],a2[6];
  load_coefs(Pc,b0,b1,b2,a1,a2);
  float z1[6]={0,0,0,0,0,0}, z2[6]={0,0,0,0,0,0};

  if (sub < CCHUNK){
    const float4* xp = (const float4*)(x + ch*T + sub*LCHUNK);
    for (int j=0;j<LCHUNK/4;j++){
      float4 v = xp[j];
      bq_step(b0,b1,b2,a1,a2,z1,z2,v.x);
      bq_step(b0,b1,b2,a1,a2,z1,z2,v.y);
      bq_step(b0,b1,b2,a1,a2,z1,z2,v.z);
      bq_step(b0,b1,b2,a1,a2,z1,z2,v.w);
    }
    float* vo = ws + OFS_V + (ch*CCHUNK + sub)*12;
    #pragma unroll
    for (int k=0;k<6;k++){ vo[2*k]=z1[k]; vo[2*k+1]=z2[k]; }
  } else {
    int j = sub - CCHUNK;                    // unit state index 0..11
    if ((j & 1)==0) z1[j>>1]=1.0f; else z2[j>>1]=1.0f;
    for (int t=0;t<LCHUNK;t++) bq_step(b0,b1,b2,a1,a2,z1,z2,0.0f);
    float* mo = ws + OFS_M + ch*144 + j*12;  // column j
    #pragma unroll
    for (int k=0;k<6;k++){ mo[2*k]=z1[k]; mo[2*k+1]=z2[k]; }
  }
}

__global__ __launch_bounds__(64,1) void k_chunk2(float* __restrict__ ws){
  int ch = threadIdx.x;
  if (ch >= NCH) return;
  const float* M = ws + OFS_M + ch*144;
  const float* V = ws + OFS_V + ch*CCHUNK*12;
  float*       Z = ws + OFS_Z + ch*CCHUNK*12;
  // hoist M into registers (aliasing with Z writes otherwise forces reloads)
  float Mr[144];
  #pragma unroll
  for (int i=0;i<144;i++) Mr[i]=M[i];
  float z[12], vbuf[12];
  #pragma unroll
  for (int i=0;i<12;i++) z[i]=0.0f;
  #pragma unroll
  for (int i=0;i<12;i++) vbuf[i]=V[i];
  for (int c=0;c<CCHUNK;c++){
    #pragma unroll
    for (int i=0;i<12;i++) Z[c*12+i]=z[i];
    float zn[12];
    #pragma unroll
    for (int i=0;i<12;i++) zn[i]=vbuf[i];
    if (c+1<CCHUNK){
      #pragma unroll
      for (int i=0;i<12;i++) vbuf[i]=V[(c+1)*12+i];
    }
    #pragma unroll
    for (int j=0;j<12;j++){
      float zj = z[j];
      #pragma unroll
      for (int i=0;i<12;i++) zn[i] = fmaf(Mr[j*12+i], zj, zn[i]);
    }
    #pragma unroll
    for (int i=0;i<12;i++) z[i]=zn[i];
  }
}

// pass 3: re-run chunks with correct init; write biquad out (A), target (B1),
// and per-8-group min-affine composed intercepts (12-float records, 9 used):
//   F_8(g) = min_{j=0..8}( aA^j aR^(8-j) g + beta_j )  -- EXACT
__global__ __launch_bounds__(64,1) void k_chunk3(const float* __restrict__ x, float* __restrict__ ws){
  int tg = blockIdx.x*64 + threadIdx.x;      // 4096
  int ch = tg >> 7, c = tg & (CCHUNK-1);
  const float* Pc = ws + OFS_P + ch*64;
  float b0[6],b1[6],b2[6],a1[6],a2[6];
  load_coefs(Pc,b0,b1,b2,a1,a2);
  float thr = Pc[30], rt = Pc[31];
  float aA = Pc[32], aR = Pc[33];
  float kA = 1.0f - aA, kR = 1.0f - aR;
  const float* Zi = ws + OFS_Z + (ch*CCHUNK + c)*12;
  float z1[6], z2[6];
  #pragma unroll
  for (int k=0;k<6;k++){ z1[k]=Zi[2*k]; z2[k]=Zi[2*k+1]; }
  const float4* xp = (const float4*)(x + ch*T + c*LCHUNK);
  float4* Ao  = (float4*)(ws + OFS_A  + (size_t)ch*T + c*LCHUNK);
  float4* B1o = (float4*)(ws + OFS_B1 + (size_t)ch*T + c*LCHUNK);
  float*  Ig  = ws + OFS_I + (size_t)ch*98304;

  for (int gg=0; gg<64; gg++){
    float4 v0 = xp[2*gg], v1 = xp[2*gg+1];
    float ya[8], Tv[8];
    ya[0]=bq_step(b0,b1,b2,a1,a2,z1,z2,v0.x);
    ya[1]=bq_step(b0,b1,b2,a1,a2,z1,z2,v0.y);
    ya[2]=bq_step(b0,b1,b2,a1,a2,z1,z2,v0.z);
    ya[3]=bq_step(b0,b1,b2,a1,a2,z1,z2,v0.w);
    ya[4]=bq_step(b0,b1,b2,a1,a2,z1,z2,v1.x);
    ya[5]=bq_step(b0,b1,b2,a1,a2,z1,z2,v1.y);
    ya[6]=bq_step(b0,b1,b2,a1,a2,z1,z2,v1.z);
    ya[7]=bq_step(b0,b1,b2,a1,a2,z1,z2,v1.w);
    #pragma unroll
    for (int s=0;s<8;s++)
      Tv[s] = fminf(0.0f, (thr - 6.0205999132796239f*log2f(fabsf(ya[s])+1e-6f))*rt);
    Ao[2*gg]   = make_float4(ya[0],ya[1],ya[2],ya[3]);
    Ao[2*gg+1] = make_float4(ya[4],ya[5],ya[6],ya[7]);
    B1o[2*gg]   = make_float4(Tv[0],Tv[1],Tv[2],Tv[3]);
    B1o[2*gg+1] = make_float4(Tv[4],Tv[5],Tv[6],Tv[7]);
    // DP: compose 8 min-affine steps; beta[j] = min intercept with j attack-steps
    float bb[9];
    bb[0] = kR*Tv[0]; bb[1] = kA*Tv[0];
    #pragma unroll
    for (int s=1;s<8;s++){
      float bA = kA*Tv[s], bR = kR*Tv[s];
      bb[s+1] = fmaf(aA, bb[s], bA);
      #pragma unroll
      for (int j=7;j>=1;j--){
        if (j<=s) bb[j] = fminf(fmaf(aA, bb[j-1], bA), fmaf(aR, bb[j], bR));
      }
      bb[0] = fmaf(aR, bb[0], bR);
    }
    int G = c*64 + gg;                         // global group index
    float* ig = Ig + (G>>5)*384 + (G&31)*12;   // block-major 12-float records
    *(float4*)(ig)   = make_float4(bb[0],bb[1],bb[2],bb[3]);
    *(float4*)(ig+4) = make_float4(bb[4],bb[5],bb[6],bb[7]);
    *(float4*)(ig+8) = make_float4(bb[8],0.0f,0.0f,0.0f);
  }
}

// ---------------- fused compressor-scan + freeverb --------------------------
// R17 = exact R10 structure (best measured: k_verb 634us), unchanged:
// SB=256 blocks, 3 barriers/iter.
// Waves 0-3: phase A (LDS-only): g recovery (2x ds_read_b128 target loads),
//   gain, comb gather into haloed cH; phase B1: x prefetch, VH=8-tap FIR +
//   comb writes, allpass stages 1-3; phase B2: stage-4 (L=225) with 31-sample
//   cross-lane handoff via xfer + halo copy for next block.
// Wave 4: phase A: LDS-write staged I/B1 regs; phase B1: load (i+2) to regs,
//   lane 256 scans block i+1 via the composed group operator; B2: idle.
// Delay-base advance: double wrap (L=225 < SB=256).
// (7 structural variants R11-R16 all regressed 719-1070us; the cost is the
// per-phase serial LDS-latency chain, and every variant lengthened it.)

__global__ __launch_bounds__(320) void k_verb(float* __restrict__ ws){
  const int LC[8] = {1116,1188,1277,1356,1422,1491,1557,1617};
  const int COFF[8] = {0,1116,2304,3581,4937,6359,7850,9407};
  const int LA[4] = {556,441,341,225};
  const int AOFF[4] = {0,556,997,1338};
  int ch = blockIdx.x, tid = threadIdx.x;
  __shared__ float cb[11024];
  __shared__ float ab[1563];
  __shared__ float cH[8][264];     // [k][8 halo + 256]
  __shared__ float xts[256];
  __shared__ float B1st[2][256];   // target staging, dbuf
  __shared__ float IldS[384];      // 32 group records x 12
  __shared__ float gB[2][32];      // group-boundary g, dbuf
  __shared__ float xfer[32];       // stage-3 outputs for samples 225..255
  const float* Pc = ws + OFS_P + ch*64;
  float fb = Pc[34], damp = Pc[35], wet1 = Pc[36], dryk = Pc[37];
  float aA = Pc[32], aR = Pc[33];
  float kA = 1.0f - aA, kR = 1.0f - aR;
  float omd = 1.0f - damp;
  float* Aio = ws + OFS_A + (size_t)ch*T;
  const float* B1c = ws + OFS_B1 + (size_t)ch*T;
  const float* IG  = ws + OFS_I + (size_t)ch*98304;
  for (int i=tid;i<11024;i+=320) cb[i]=0.0f;
  for (int i=tid;i<1563;i+=320)  ab[i]=0.0f;
  for (int i=tid;i<8*264;i+=320) ((float*)cH)[i]=0.0f;
  bool scanw = (tid >= 256);
  int sl = tid - 256;
  // FIR weights damp^d
  float w[VH];
  { float pw = 1.0f;
    #pragma unroll
    for (int d=0;d<VH;d++){ w[d]=pw; pw*=damp; } }
  // scan slopes s_j = aA^j aR^(8-j)
  float sj[9];
  { float pA = 1.0f;
    #pragma unroll
    for (int j=0;j<9;j++){ sj[j]=pA; pA*=aA; }
    float pR = 1.0f;
    #pragma unroll
    for (int j=8;j>=0;j--){ sj[j]*=pR; pR*=aR; } }
  int cbb[8] = {0,0,0,0,0,0,0,0};
  int abb[4] = {0,0,0,0};
  float gcarry = 0.0f;
  float4 iR0, iR1, bR;
  float xv = 0.0f;

  // ---- prologue: IldS=I(0); B1st[0]=t(0), B1st[1]=t(1); regs=I(1); xv=x(0) ----
  if (scanw){
    const float4* isrc = (const float4*)(IG);
    float4* idst = (float4*)IldS;
    idst[sl] = isrc[sl];
    if (sl < 32) idst[64+sl] = isrc[64+sl];
    iR0 = isrc[96+sl];
    if (sl < 32) iR1 = isrc[96+64+sl];
    const float4* bsrc = (const float4*)(B1c);
    ((float4*)B1st[0])[sl] = bsrc[sl];
    ((float4*)B1st[1])[sl] = bsrc[64+sl];
  }
  if (tid < 256) xv = Aio[tid];
  __syncthreads();
  if (tid == 256){
    float g = 0.0f;
    for (int m=0;m<32;m++){
      gB[0][m] = g;
      const float* Ip = &IldS[m*12];
      float f0=fmaf(sj[0],g,Ip[0]), f1=fmaf(sj[1],g,Ip[1]), f2=fmaf(sj[2],g,Ip[2]);
      float f3=fmaf(sj[3],g,Ip[3]), f4=fmaf(sj[4],g,Ip[4]), f5=fmaf(sj[5],g,Ip[5]);
      float f6=fmaf(sj[6],g,Ip[6]), f7=fmaf(sj[7],g,Ip[7]), f8=fmaf(sj[8],g,Ip[8]);
      g = fminf(fminf(fminf(f0,f1),fminf(f2,f3)),
                fminf(fminf(f4,f5),fminf(fminf(f6,f7),f8)));
    }
    gcarry = g;
  }
  __syncthreads();

  for (int i=0;i<NBLK;i++){
    int t0 = i<<8;
    int p = i & 1;
    float xt = 0.0f, acc = 0.0f, a = 0.0f;
    // ---------- phase A (LDS-only) ----------
    if (tid < 256){
      int m = tid>>3, r = tid&7;
      float g = gB[p][m];
      const float* Bl = B1st[p] + (m<<3);
      float4 q0 = *(const float4*)(Bl);
      float4 q1 = *(const float4*)(Bl+4);
      float tv[8] = {q0.x,q0.y,q0.z,q0.w,q1.x,q1.y,q1.z,q1.w};
      #pragma unroll
      for (int s=0;s<8;s++){
        if (s<=r){
          float tt = tv[s];
          g = fminf(fmaf(aA,g,kA*tt), fmaf(aR,g,kR*tt));
        }
      }
      xt = xv * exp2f(g*0.16609640474436813f) * 0.015f;
      xts[tid] = xt;
      #pragma unroll
      for (int k=0;k<8;k++){
        int idx = cbb[k]+tid; if (idx>=LC[k]) idx-=LC[k];
        float o = cb[COFF[k]+idx];
        cH[k][VH+tid] = omd*o;
        acc += o;
      }
    } else if (i+1 < NBLK){
      // wave4: LDS-write staged regs: IldS = I(i+1); B1st[(i+1)&1] = t(i+1)
      float4* idst = (float4*)IldS;
      idst[sl] = iR0;
      if (sl < 32) idst[64+sl] = iR1;
      if (i >= 1) ((float4*)B1st[(i+1)&1])[sl] = bR;
    }
    __syncthreads();
    // ---------- phase B1: issue globals first, then compute ----------
    if (tid < 256){
      if (i+1 < NBLK) xv = Aio[t0+256+tid];    // prefetch next x (drain covered)
      // FIR damping + comb writes
      #pragma unroll
      for (int k=0;k<8;k++){
        float s = 0.0f;
        #pragma unroll
        for (int d=0;d<VH;d++) s = fmaf(w[d], cH[k][VH+tid-d], s);
        int idx = cbb[k]+tid; if (idx>=LC[k]) idx-=LC[k];
        cb[COFF[k]+idx] = fmaf(fb, s, xt);
      }
      // allpass stages 1-3, per-lane registers (slots unique: SB <= L)
      a = acc;
      #pragma unroll
      for (int j=0;j<3;j++){
        int idx = abb[j]+tid; if (idx>=LA[j]) idx-=LA[j];
        float bv = ab[AOFF[j]+idx];
        ab[AOFF[j]+idx] = fmaf(0.5f, bv, a);
        a = bv - a;
      }
      if (tid >= 225) xfer[tid-225] = a;
    } else {
      if (i+2 < NBLK){                         // stage block i+2 into regs
        const float4* isrc = (const float4*)(IG + (size_t)(i+2)*384);
        iR0 = isrc[sl];
        if (sl < 32) iR1 = isrc[64+sl];
        const float4* bsrc = (const float4*)(B1c + (size_t)(i+2)*SB);
        bR = bsrc[sl];
      }
      if (tid == 256 && i+1 < NBLK){           // scan block i+1
        int q = (i+1)&1;
        float g = gcarry;
        #pragma unroll 4
        for (int m=0;m<32;m++){
          gB[q][m] = g;
          const float* Ip = &IldS[m*12];
          float f0=fmaf(sj[0],g,Ip[0]), f1=fmaf(sj[1],g,Ip[1]), f2=fmaf(sj[2],g,Ip[2]);
          float f3=fmaf(sj[3],g,Ip[3]), f4=fmaf(sj[4],g,Ip[4]), f5=fmaf(sj[5],g,Ip[5]);
          float f6=fmaf(sj[6],g,Ip[6]), f7=fmaf(sj[7],g,Ip[7]), f8=fmaf(sj[8],g,Ip[8]);
          g = fminf(fminf(fminf(f0,f1),fminf(f2,f3)),
                    fminf(fminf(f4,f5),fminf(fminf(f6,f7),f8)));
        }
        gcarry = g;
      }
    }
    __syncthreads();
    // ---------- phase B2: allpass stage 4 (L=225) + output ----------
    if (tid < 225){
      int idx = abb[3]+tid; if (idx>=225) idx-=225;
      float bv = ab[AOFF[3]+idx];
      float b  = fmaf(0.5f, bv, a);
      float y  = bv - a;
      Aio[t0+tid] = fmaf(y, wet1, xts[tid]*dryk);
      if (tid < 31){
        float a2 = xfer[tid];              // sample tid+225
        float y2 = b - a2;
        ab[AOFF[3]+idx] = fmaf(0.5f, b, a2);
        Aio[t0+225+tid] = fmaf(y2, wet1, xts[225+tid]*dryk);
      } else {
        ab[AOFF[3]+idx] = b;
      }
    } else if (tid >= 232 && tid < 288){
      int q = tid-232; int k = q/7, d = q%7;   // halo: prev block samples 249..255
      cH[k][1+d] = cH[k][257+d];
    }
    #pragma unroll
    for (int k=0;k<8;k++){ cbb[k]+=SB; if (cbb[k]>=LC[k]) cbb[k]-=LC[k]; }
    #pragma unroll
    for (int j=0;j<4;j++){
      abb[j]+=SB;
      if (abb[j]>=LA[j]) abb[j]-=LA[j];
      if (abb[j]>=LA[j]) abb[j]-=LA[j];   // L=225 < SB=256 needs 2nd wrap
    }
    __syncthreads();
  }
}

// ---------------- pan mix ----------------

__global__ void k_mix(const float* __restrict__ ws, float* __restrict__ out){
  int id = blockIdx.x*256 + threadIdx.x;   // 4*65536
  int t = id & (T-1), b = id >> 16;
  const float* Av = ws + OFS_A + (size_t)b*8*T + t;
  const float* P = ws + OFS_P;
  float s0=0.0f, s1=0.0f;
  #pragma unroll
  for (int n=0;n<8;n++){
    float v = Av[(size_t)n*T];
    int ch = b*8+n;
    s0 = fmaf(v, P[ch*64+38], s0);
    s1 = fmaf(v, P[ch*64+39], s1);
  }
  out[b*2*T + t]     = s0;
  out[b*2*T + T + t] = s1;
}

extern "C" void kernel_launch(void* const* d_in, const int* in_sizes, int n_in,
                              void* d_out, int out_size, void* d_ws, size_t ws_size,
                              hipStream_t stream) {
  const float* x = (const float*)d_in[0];
  const float* p = (const float*)d_in[1];
  float* out = (float*)d_out;
  float* ws  = (float*)d_ws;

  k_params<<<1, 64, 0, stream>>>(p, ws, out + 4*2*T);
  k_chunk1<<<70, 64, 0, stream>>>(x, ws);
  k_chunk2<<<1, 64, 0, stream>>>(ws);
  k_chunk3<<<64, 64, 0, stream>>>(x, ws);
  k_verb  <<<NCH, 320, 0, stream>>>(ws);
  k_mix   <<<(4*T)/256, 256, 0, stream>>>(ws, out);
}

// Round 10
// 841.226 us; speedup vs baseline: 1.5750x; 1.0693x over previous
//
#include <hip/hip_runtime.h>
#include <math.h>

#define T 65536
#define NCH 32
#define LCHUNK 512
#define CCHUNK 128
#define SB 256            // reverb block length (65536 = 256 blocks of 256)
#define NBLK 256
#define VH 8              // damping FIR taps (damp<=0.4: 0.4^8 ~ 6.5e-4)

// ws layout (float offsets).
#define OFS_A  0          // 32*65536: biquad out -> final pre-pan signal (in-place)
#define OFS_B1 2097152    // 32*65536: compressor target per sample
#define OFS_I  4194304    // 32*256*384: per-block group records (12 floats/group, 9 used)
#define OFS_P  7340032    // 32*64 derived params (k_mix reads 38/39)

// ---------------- helpers ----------------

__device__ __forceinline__ float bq_step(const float* b0, const float* b1, const float* b2,
                                         const float* a1, const float* a2,
                                         float* z1, float* z2, float s){
  #pragma unroll
  for (int k=0;k<6;k++){
    float y = fmaf(b0[k], s, z1[k]);
    z1[k] = fmaf(b1[k], s, fmaf(-a1[k], y, z2[k]));
    z2[k] = fmaf(b2[k], s, -a2[k]*y);
    s = y;
  }
  return s;
}

__device__ __forceinline__ void load_coefs(const float* Pc, float* b0, float* b1, float* b2,
                                           float* a1, float* a2){
  #pragma unroll
  for (int k=0;k<6;k++){
    b0[k]=Pc[k]; b1[k]=Pc[6+k]; b2[k]=Pc[12+k]; a1[k]=Pc[18+k]; a2[k]=Pc[24+k];
  }
}

__device__ void shelf_store(double fc, double g, double s, float* PcS, int k){
  double A  = pow(10.0, g/40.0);
  double w  = 2.0*3.14159265358979323846*fc/44100.0;
  double cw = cos(w);
  double al = sin(w)*0.70710678118654752;
  double sq = 2.0*sqrt(A)*al;
  double b0 = A*((A+1.0) + s*(A-1.0)*cw + sq);
  double b1 = -2.0*s*A*((A-1.0) + s*(A+1.0)*cw);
  double b2 = A*((A+1.0) + s*(A-1.0)*cw - sq);
  double a0 = (A+1.0) - s*(A-1.0)*cw + sq;
  double a1 = 2.0*s*((A-1.0) - s*(A+1.0)*cw);
  double a2 = (A+1.0) - s*(A-1.0)*cw - sq;
  PcS[k]    = (float)(b0/a0);
  PcS[6+k]  = (float)(b1/a0);
  PcS[12+k] = (float)(b2/a0);
  PcS[18+k] = (float)(a1/a0);
  PcS[24+k] = (float)(a2/a0);
}

__device__ void peak_store(double fc, double g, double q, float* PcS, int k){
  double A  = pow(10.0, g/40.0);
  double w  = 2.0*3.14159265358979323846*fc/44100.0;
  double cw = cos(w);
  double al = sin(w)/(2.0*q);
  double b0 = 1.0+al*A, b1 = -2.0*cw, b2 = 1.0-al*A;
  double a0 = 1.0+al/A, a1 = -2.0*cw, a2 = 1.0-al/A;
  PcS[k]    = (float)(b0/a0);
  PcS[6+k]  = (float)(b1/a0);
  PcS[12+k] = (float)(b2/a0);
  PcS[18+k] = (float)(a1/a0);
  PcS[24+k] = (float)(a2/a0);
}

// ---------------- fused per-channel pipeline --------------------------------
// R18 (resubmit after infra failure; audited: all barriers top-level/uniform,
// LDS aliasing disjoint per stage with barriers between, shfl confined to
// wave 0, global write->read ordered by vmcnt drain):
// one block per channel runs the WHOLE pipeline: params (threads 0-8,
// double math verbatim from k_params) -> chunk1 (threads 0-139, V/M to LDS)
// -> chunk2 (12-lane shfl scan, same j-ascending accumulation = bit-identical)
// -> chunk3 (threads 0-127, A/B1/I to global) -> verbatim R10 verb body.
// Front-end scratch (V 1536 + Z 1536 + M 144 + Pc 40 floats) aliases into cb,
// which is zeroed before the verb loop anyway. Rationale: total - k_verb has
// been a constant ~260us across all rounds while front-end compute is ~30us
// by arithmetic -> the rest is 5 serialized launch/drain gaps. 6 launches -> 2.

__global__ __launch_bounds__(320) void k_main(const float* __restrict__ x,
                                              const float* __restrict__ p,
                                              float* __restrict__ ws,
                                              float* __restrict__ pout){
  const int LC[8] = {1116,1188,1277,1356,1422,1491,1557,1617};
  const int COFF[8] = {0,1116,2304,3581,4937,6359,7850,9407};
  const int LA[4] = {556,441,341,225};
  const int AOFF[4] = {0,556,997,1338};
  int ch = blockIdx.x, tid = threadIdx.x;
  __shared__ float cb[11024];
  __shared__ float ab[1563];
  __shared__ float cH[8][264];     // [k][8 halo + 256]
  __shared__ float xts[256];
  __shared__ float B1st[2][256];   // target staging, dbuf
  __shared__ float IldS[384];      // 32 group records x 12
  __shared__ float gB[2][32];      // group-boundary g, dbuf
  __shared__ float xfer[32];       // stage-3 outputs for samples 225..255
  // front-end scratch aliased into cb (zeroed later)
  float* Vls = cb;                 // 128*12
  float* Zls = cb + 1536;          // 128*12
  float* Mls = cb + 3072;          // 12*12
  float* PcS = cb + 3216;          // 40

  float* Aio = ws + OFS_A + (size_t)ch*T;
  const float* B1c = ws + OFS_B1 + (size_t)ch*T;
  const float* IG  = ws + OFS_I + (size_t)ch*98304;
  const float* pf = p + ch*24;

  // ---------------- stage 0: params (verbatim k_params math) ----------------
  if (tid == 0){
    double gain_in = (double)pf[0]*60.0 - 48.0;
    double hp_fc   = (double)pf[1]*350.0;
    double gin = pow(10.0, gain_in/20.0);
    double K = tan(3.14159265358979323846*hp_fc/44100.0);
    double a1=(K-1.0)/(K+1.0), b0=1.0/(1.0+K);
    PcS[0]  = (float)(b0*gin);
    PcS[6]  = (float)(-b0*gin);
    PcS[12] = 0.0f;
    PcS[18] = (float)a1;
    PcS[24] = 0.0f;
  } else if (tid == 1){
    double lp_fc = (double)pf[2]*19000.0 + 3000.0;
    double K = tan(3.14159265358979323846*lp_fc/44100.0);
    double a1=(K-1.0)/(K+1.0), b0=K/(1.0+K);
    PcS[1]  = (float)b0;
    PcS[7]  = (float)b0;
    PcS[13] = 0.0f;
    PcS[19] = (float)a1;
    PcS[25] = 0.0f;
  } else if (tid == 2){
    shelf_store((double)pf[3]*14500.0 + 1500.0, (double)pf[4]*30.0 - 15.0,  1.0, PcS, 2);
  } else if (tid == 3){
    shelf_store((double)pf[5]*420.0 + 30.0,    (double)pf[6]*30.0 - 15.0, -1.0, PcS, 3);
  } else if (tid == 4){
    peak_store((double)pf[7]*6400.0 + 600.0,  (double)pf[8]*30.0 - 15.0,
               (double)pf[9]*2.5 + 0.5, PcS, 4);
  } else if (tid == 5){
    peak_store((double)pf[10]*2300.0 + 200.0, (double)pf[11]*30.0 - 15.0,
               (double)pf[12]*2.5 + 0.5, PcS, 5);
  } else if (tid == 6){
    double c_thr = (double)pf[13]*30.0 - 20.0;
    double c_rat = (double)pf[14]*19.0 + 1.0;
    double c_att = (double)pf[15]*29.0 + 1.0;
    double c_rel = (double)pf[16]*3900.0 + 100.0;
    PcS[30] = (float)c_thr;
    PcS[31] = (float)(1.0 - 1.0/c_rat);
    PcS[32] = (float)exp(-1.0/(c_att*0.001*44100.0));
    PcS[33] = (float)exp(-1.0/(c_rel*0.001*44100.0));
  } else if (tid == 7){
    double fb   = (double)pf[17]*0.28 + 0.7;
    double damp = (double)pf[18]*0.4;
    double wet1 = 3.0*(double)pf[19]*0.5*(1.0+(double)pf[21]);
    double dryg = 2.0*(double)pf[20];
    double gain_out = (double)pf[22]*60.0 - 48.0;
    double gout = pow(10.0, gain_out/20.0);
    double pan  = (double)pf[23]*0.4 + 0.3;
    PcS[34] = (float)fb;
    PcS[35] = (float)damp;
    PcS[36] = (float)(wet1*gout);
    PcS[37] = (float)(dryg*gout/0.015);
    PcS[38] = (float)cos(pan*1.57079632679489662);
    PcS[39] = (float)sin(pan*1.57079632679489662);
  } else if (tid == 8){
    float* po = pout + ch*24;
    po[0]=(float)((double)pf[0]*60.0-48.0);   po[1]=(float)((double)pf[1]*350.0);
    po[2]=(float)((double)pf[2]*19000.0+3000.0); po[3]=(float)((double)pf[3]*14500.0+1500.0);
    po[4]=(float)((double)pf[4]*30.0-15.0);   po[5]=(float)((double)pf[5]*420.0+30.0);
    po[6]=(float)((double)pf[6]*30.0-15.0);   po[7]=(float)((double)pf[7]*6400.0+600.0);
    po[8]=(float)((double)pf[8]*30.0-15.0);   po[9]=(float)((double)pf[9]*2.5+0.5);
    po[10]=(float)((double)pf[10]*2300.0+200.0); po[11]=(float)((double)pf[11]*30.0-15.0);
    po[12]=(float)((double)pf[12]*2.5+0.5);   po[13]=(float)((double)pf[13]*30.0-20.0);
    po[14]=(float)((double)pf[14]*19.0+1.0);  po[15]=(float)((double)pf[15]*29.0+1.0);
    po[16]=(float)((double)pf[16]*3900.0+100.0);
    po[17]=pf[17]; po[18]=pf[18]; po[19]=pf[19]; po[20]=pf[20]; po[21]=pf[21];
    po[22]=(float)((double)pf[22]*60.0-48.0); po[23]=(float)((double)pf[23]*0.4+0.3);
  }
  __syncthreads();

  // params to registers (all threads) + global P for k_mix
  float fb = PcS[34], damp = PcS[35], wet1 = PcS[36], dryk = PcS[37];
  float aA = PcS[32], aR = PcS[33];
  float thr = PcS[30], rt = PcS[31];
  float kA = 1.0f - aA, kR = 1.0f - aR;
  float omd = 1.0f - damp;
  float b0[6],b1[6],b2[6],a1[6],a2[6];
  if (tid < 140) load_coefs(PcS,b0,b1,b2,a1,a2);
  if (tid < 40) (ws + OFS_P + ch*64)[tid] = PcS[tid];

  // ---------------- stage 1: chunk1 (V, M into LDS) ----------------
  if (tid < 140){
    float z1[6]={0,0,0,0,0,0}, z2[6]={0,0,0,0,0,0};
    if (tid < CCHUNK){
      const float4* xp = (const float4*)(x + ch*T + tid*LCHUNK);
      for (int j=0;j<LCHUNK/4;j++){
        float4 v = xp[j];
        bq_step(b0,b1,b2,a1,a2,z1,z2,v.x);
        bq_step(b0,b1,b2,a1,a2,z1,z2,v.y);
        bq_step(b0,b1,b2,a1,a2,z1,z2,v.z);
        bq_step(b0,b1,b2,a1,a2,z1,z2,v.w);
      }
      #pragma unroll
      for (int k=0;k<6;k++){ Vls[tid*12+2*k]=z1[k]; Vls[tid*12+2*k+1]=z2[k]; }
    } else {
      int j = tid - CCHUNK;                  // unit state index 0..11
      if ((j & 1)==0) z1[j>>1]=1.0f; else z2[j>>1]=1.0f;
      for (int t=0;t<LCHUNK;t++) bq_step(b0,b1,b2,a1,a2,z1,z2,0.0f);
      #pragma unroll
      for (int k=0;k<6;k++){ Mls[j*12+2*k]=z1[k]; Mls[j*12+2*k+1]=z2[k]; }
    }
  }
  __syncthreads();

  // ---------------- stage 2: chunk2 scan (12-lane shfl, j-ascending) -------
  if (tid < 64){
    int i = tid; bool act = (i < 12);
    float Mr_[12];
    #pragma unroll
    for (int j=0;j<12;j++) Mr_[j] = act ? Mls[j*12+i] : 0.0f;
    float z = 0.0f;
    for (int c=0;c<CCHUNK;c++){
      if (act) Zls[c*12+i] = z;
      float zn = act ? Vls[c*12+i] : 0.0f;
      #pragma unroll
      for (int j=0;j<12;j++) zn = fmaf(Mr_[j], __shfl(z, j), zn);
      z = zn;
    }
  }
  __syncthreads();

  // ---------------- stage 3: chunk3 (A, B1, I to global) ----------------
  if (tid < CCHUNK){
    int c = tid;
    float z1[6], z2[6];
    #pragma unroll
    for (int k=0;k<6;k++){ z1[k]=Zls[c*12+2*k]; z2[k]=Zls[c*12+2*k+1]; }
    const float4* xp = (const float4*)(x + ch*T + c*LCHUNK);
    float4* Ao  = (float4*)(ws + OFS_A  + (size_t)ch*T + c*LCHUNK);
    float4* B1o = (float4*)(ws + OFS_B1 + (size_t)ch*T + c*LCHUNK);
    float*  Ig  = ws + OFS_I + (size_t)ch*98304;
    for (int gg=0; gg<64; gg++){
      float4 v0 = xp[2*gg], v1 = xp[2*gg+1];
      float ya[8], Tv[8];
      ya[0]=bq_step(b0,b1,b2,a1,a2,z1,z2,v0.x);
      ya[1]=bq_step(b0,b1,b2,a1,a2,z1,z2,v0.y);
      ya[2]=bq_step(b0,b1,b2,a1,a2,z1,z2,v0.z);
      ya[3]=bq_step(b0,b1,b2,a1,a2,z1,z2,v0.w);
      ya[4]=bq_step(b0,b1,b2,a1,a2,z1,z2,v1.x);
      ya[5]=bq_step(b0,b1,b2,a1,a2,z1,z2,v1.y);
      ya[6]=bq_step(b0,b1,b2,a1,a2,z1,z2,v1.z);
      ya[7]=bq_step(b0,b1,b2,a1,a2,z1,z2,v1.w);
      #pragma unroll
      for (int s=0;s<8;s++)
        Tv[s] = fminf(0.0f, (thr - 6.0205999132796239f*log2f(fabsf(ya[s])+1e-6f))*rt);
      Ao[2*gg]   = make_float4(ya[0],ya[1],ya[2],ya[3]);
      Ao[2*gg+1] = make_float4(ya[4],ya[5],ya[6],ya[7]);
      B1o[2*gg]   = make_float4(Tv[0],Tv[1],Tv[2],Tv[3]);
      B1o[2*gg+1] = make_float4(Tv[4],Tv[5],Tv[6],Tv[7]);
      // DP: compose 8 min-affine steps
      float bb[9];
      bb[0] = kR*Tv[0]; bb[1] = kA*Tv[0];
      #pragma unroll
      for (int s=1;s<8;s++){
        float bA = kA*Tv[s], bR = kR*Tv[s];
        bb[s+1] = fmaf(aA, bb[s], bA);
        #pragma unroll
        for (int j=7;j>=1;j--){
          if (j<=s) bb[j] = fminf(fmaf(aA, bb[j-1], bA), fmaf(aR, bb[j], bR));
        }
        bb[0] = fmaf(aR, bb[0], bR);
      }
      int G = c*64 + gg;
      float* ig = Ig + (G>>5)*384 + (G&31)*12;
      *(float4*)(ig)   = make_float4(bb[0],bb[1],bb[2],bb[3]);
      *(float4*)(ig+4) = make_float4(bb[4],bb[5],bb[6],bb[7]);
      *(float4*)(ig+8) = make_float4(bb[8],0.0f,0.0f,0.0f);
    }
  }
  __syncthreads();   // vmcnt drain: stage-3 global writes visible to verb reads

  // ---------------- verb: verbatim R10 body ----------------
  for (int i=tid;i<11024;i+=320) cb[i]=0.0f;
  for (int i=tid;i<1563;i+=320)  ab[i]=0.0f;
  for (int i=tid;i<8*264;i+=320) ((float*)cH)[i]=0.0f;
  bool scanw = (tid >= 256);
  int sl = tid - 256;
  // FIR weights damp^d
  float w[VH];
  { float pw = 1.0f;
    #pragma unroll
    for (int d=0;d<VH;d++){ w[d]=pw; pw*=damp; } }
  // scan slopes s_j = aA^j aR^(8-j)
  float sj[9];
  { float pA = 1.0f;
    #pragma unroll
    for (int j=0;j<9;j++){ sj[j]=pA; pA*=aA; }
    float pR = 1.0f;
    #pragma unroll
    for (int j=8;j>=0;j--){ sj[j]*=pR; pR*=aR; } }
  int cbb[8] = {0,0,0,0,0,0,0,0};
  int abb[4] = {0,0,0,0};
  float gcarry = 0.0f;
  float4 iR0, iR1, bR;
  float xv = 0.0f;

  // ---- prologue: IldS=I(0); B1st[0]=t(0), B1st[1]=t(1); regs=I(1); xv=x(0) ----
  if (scanw){
    const float4* isrc = (const float4*)(IG);
    float4* idst = (float4*)IldS;
    idst[sl] = isrc[sl];
    if (sl < 32) idst[64+sl] = isrc[64+sl];
    iR0 = isrc[96+sl];
    if (sl < 32) iR1 = isrc[96+64+sl];
    const float4* bsrc = (const float4*)(B1c);
    ((float4*)B1st[0])[sl] = bsrc[sl];
    ((float4*)B1st[1])[sl] = bsrc[64+sl];
  }
  if (tid < 256) xv = Aio[tid];
  __syncthreads();
  if (tid == 256){
    float g = 0.0f;
    for (int m=0;m<32;m++){
      gB[0][m] = g;
      const float* Ip = &IldS[m*12];
      float f0=fmaf(sj[0],g,Ip[0]), f1=fmaf(sj[1],g,Ip[1]), f2=fmaf(sj[2],g,Ip[2]);
      float f3=fmaf(sj[3],g,Ip[3]), f4=fmaf(sj[4],g,Ip[4]), f5=fmaf(sj[5],g,Ip[5]);
      float f6=fmaf(sj[6],g,Ip[6]), f7=fmaf(sj[7],g,Ip[7]), f8=fmaf(sj[8],g,Ip[8]);
      g = fminf(fminf(fminf(f0,f1),fminf(f2,f3)),
                fminf(fminf(f4,f5),fminf(fminf(f6,f7),f8)));
    }
    gcarry = g;
  }
  __syncthreads();

  for (int i=0;i<NBLK;i++){
    int t0 = i<<8;
    int p2 = i & 1;
    float xt = 0.0f, acc = 0.0f, a = 0.0f;
    // ---------- phase A (LDS-only) ----------
    if (tid < 256){
      int m = tid>>3, r = tid&7;
      float g = gB[p2][m];
      const float* Bl = B1st[p2] + (m<<3);
      float4 q0 = *(const float4*)(Bl);
      float4 q1 = *(const float4*)(Bl+4);
      float tv[8] = {q0.x,q0.y,q0.z,q0.w,q1.x,q1.y,q1.z,q1.w};
      #pragma unroll
      for (int s=0;s<8;s++){
        if (s<=r){
          float tt = tv[s];
          g = fminf(fmaf(aA,g,kA*tt), fmaf(aR,g,kR*tt));
        }
      }
      xt = xv * exp2f(g*0.16609640474436813f) * 0.015f;
      xts[tid] = xt;
      #pragma unroll
      for (int k=0;k<8;k++){
        int idx = cbb[k]+tid; if (idx>=LC[k]) idx-=LC[k];
        float o = cb[COFF[k]+idx];
        cH[k][VH+tid] = omd*o;
        acc += o;
      }
    } else if (i+1 < NBLK){
      // wave4: LDS-write staged regs: IldS = I(i+1); B1st[(i+1)&1] = t(i+1)
      float4* idst = (float4*)IldS;
      idst[sl] = iR0;
      if (sl < 32) idst[64+sl] = iR1;
      if (i >= 1) ((float4*)B1st[(i+1)&1])[sl] = bR;
    }
    __syncthreads();
    // ---------- phase B1: issue globals first, then compute ----------
    if (tid < 256){
      if (i+1 < NBLK) xv = Aio[t0+256+tid];    // prefetch next x (drain covered)
      // FIR damping + comb writes
      #pragma unroll
      for (int k=0;k<8;k++){
        float s = 0.0f;
        #pragma unroll
        for (int d=0;d<VH;d++) s = fmaf(w[d], cH[k][VH+tid-d], s);
        int idx = cbb[k]+tid; if (idx>=LC[k]) idx-=LC[k];
        cb[COFF[k]+idx] = fmaf(fb, s, xt);
      }
      // allpass stages 1-3, per-lane registers (slots unique: SB <= L)
      a = acc;
      #pragma unroll
      for (int j=0;j<3;j++){
        int idx = abb[j]+tid; if (idx>=LA[j]) idx-=LA[j];
        float bv = ab[AOFF[j]+idx];
        ab[AOFF[j]+idx] = fmaf(0.5f, bv, a);
        a = bv - a;
      }
      if (tid >= 225) xfer[tid-225] = a;
    } else {
      if (i+2 < NBLK){                         // stage block i+2 into regs
        const float4* isrc = (const float4*)(IG + (size_t)(i+2)*384);
        iR0 = isrc[sl];
        if (sl < 32) iR1 = isrc[64+sl];
        const float4* bsrc = (const float4*)(B1c + (size_t)(i+2)*SB);
        bR = bsrc[sl];
      }
      if (tid == 256 && i+1 < NBLK){           // scan block i+1
        int q = (i+1)&1;
        float g = gcarry;
        #pragma unroll 4
        for (int m=0;m<32;m++){
          gB[q][m] = g;
          const float* Ip = &IldS[m*12];
          float f0=fmaf(sj[0],g,Ip[0]), f1=fmaf(sj[1],g,Ip[1]), f2=fmaf(sj[2],g,Ip[2]);
          float f3=fmaf(sj[3],g,Ip[3]), f4=fmaf(sj[4],g,Ip[4]), f5=fmaf(sj[5],g,Ip[5]);
          float f6=fmaf(sj[6],g,Ip[6]), f7=fmaf(sj[7],g,Ip[7]), f8=fmaf(sj[8],g,Ip[8]);
          g = fminf(fminf(fminf(f0,f1),fminf(f2,f3)),
                    fminf(fminf(f4,f5),fminf(fminf(f6,f7),f8)));
        }
        gcarry = g;
      }
    }
    __syncthreads();
    // ---------- phase B2: allpass stage 4 (L=225) + output ----------
    if (tid < 225){
      int idx = abb[3]+tid; if (idx>=225) idx-=225;
      float bv = ab[AOFF[3]+idx];
      float b  = fmaf(0.5f, bv, a);
      float y  = bv - a;
      Aio[t0+tid] = fmaf(y, wet1, xts[tid]*dryk);
      if (tid < 31){
        float a2v = xfer[tid];             // sample tid+225
        float y2 = b - a2v;
        ab[AOFF[3]+idx] = fmaf(0.5f, b, a2v);
        Aio[t0+225+tid] = fmaf(y2, wet1, xts[225+tid]*dryk);
      } else {
        ab[AOFF[3]+idx] = b;
      }
    } else if (tid >= 232 && tid < 288){
      int q = tid-232; int k = q/7, d = q%7;   // halo: prev block samples 249..255
      cH[k][1+d] = cH[k][257+d];
    }
    #pragma unroll
    for (int k=0;k<8;k++){ cbb[k]+=SB; if (cbb[k]>=LC[k]) cbb[k]-=LC[k]; }
    #pragma unroll
    for (int j=0;j<4;j++){
      abb[j]+=SB;
      if (abb[j]>=LA[j]) abb[j]-=LA[j];
      if (abb[j]>=LA[j]) abb[j]-=LA[j];   // L=225 < SB=256 needs 2nd wrap
    }
    __syncthreads();
  }
}

// ---------------- pan mix ----------------

__global__ void k_mix(const float* __restrict__ ws, float* __restrict__ out){
  int id = blockIdx.x*256 + threadIdx.x;   // 4*65536
  int t = id & (T-1), b = id >> 16;
  const float* Av = ws + OFS_A + (size_t)b*8*T + t;
  const float* P = ws + OFS_P;
  float s0=0.0f, s1=0.0f;
  #pragma unroll
  for (int n=0;n<8;n++){
    float v = Av[(size_t)n*T];
    int ch = b*8+n;
    s0 = fmaf(v, P[ch*64+38], s0);
    s1 = fmaf(v, P[ch*64+39], s1);
  }
  out[b*2*T + t]     = s0;
  out[b*2*T + T + t] = s1;
}

extern "C" void kernel_launch(void* const* d_in, const int* in_sizes, int n_in,
                              void* d_out, int out_size, void* d_ws, size_t ws_size,
                              hipStream_t stream) {
  const float* x = (const float*)d_in[0];
  const float* p = (const float*)d_in[1];
  float* out = (float*)d_out;
  float* ws  = (float*)d_ws;

  k_main<<<NCH, 320, 0, stream>>>(x, p, ws, out + 4*2*T);
  k_mix <<<(4*T)/256, 256, 0, stream>>>(ws, out);
}

// Round 11
// 816.600 us; speedup vs baseline: 1.6225x; 1.0302x over previous
//
#include <hip/hip_runtime.h>
#include <math.h>

#define T 65536
#define NCH 32
#define LCHUNK 256        // chunk length (R19: 512->256 to double front-end waves)
#define CCHUNK 256        // chunks per channel
#define SB 256            // reverb block length (65536 = 256 blocks of 256)
#define NBLK 256
#define VH 8              // damping FIR taps (damp<=0.4: 0.4^8 ~ 6.5e-4)

// ws layout (float offsets).
#define OFS_A  0          // 32*65536: biquad out -> final pre-pan signal (in-place)
#define OFS_B1 2097152    // 32*65536: compressor target per sample
#define OFS_I  4194304    // 32*256*384: per-block group records (12 floats/group, 9 used)
#define OFS_P  7340032    // 32*64 derived params (k_mix reads 38/39)

// ---------------- helpers ----------------

__device__ __forceinline__ float bq_step(const float* b0, const float* b1, const float* b2,
                                         const float* a1, const float* a2,
                                         float* z1, float* z2, float s){
  #pragma unroll
  for (int k=0;k<6;k++){
    float y = fmaf(b0[k], s, z1[k]);
    z1[k] = fmaf(b1[k], s, fmaf(-a1[k], y, z2[k]));
    z2[k] = fmaf(b2[k], s, -a2[k]*y);
    s = y;
  }
  return s;
}

__device__ __forceinline__ void load_coefs(const float* Pc, float* b0, float* b1, float* b2,
                                           float* a1, float* a2){
  #pragma unroll
  for (int k=0;k<6;k++){
    b0[k]=Pc[k]; b1[k]=Pc[6+k]; b2[k]=Pc[12+k]; a1[k]=Pc[18+k]; a2[k]=Pc[24+k];
  }
}

__device__ void shelf_store(double fc, double g, double s, float* PcS, int k){
  double A  = pow(10.0, g/40.0);
  double w  = 2.0*3.14159265358979323846*fc/44100.0;
  double cw = cos(w);
  double al = sin(w)*0.70710678118654752;
  double sq = 2.0*sqrt(A)*al;
  double b0 = A*((A+1.0) + s*(A-1.0)*cw + sq);
  double b1 = -2.0*s*A*((A-1.0) + s*(A+1.0)*cw);
  double b2 = A*((A+1.0) + s*(A-1.0)*cw - sq);
  double a0 = (A+1.0) - s*(A-1.0)*cw + sq;
  double a1 = 2.0*s*((A-1.0) - s*(A+1.0)*cw);
  double a2 = (A+1.0) - s*(A-1.0)*cw - sq;
  PcS[k]    = (float)(b0/a0);
  PcS[6+k]  = (float)(b1/a0);
  PcS[12+k] = (float)(b2/a0);
  PcS[18+k] = (float)(a1/a0);
  PcS[24+k] = (float)(a2/a0);
}

__device__ void peak_store(double fc, double g, double q, float* PcS, int k){
  double A  = pow(10.0, g/40.0);
  double w  = 2.0*3.14159265358979323846*fc/44100.0;
  double cw = cos(w);
  double al = sin(w)/(2.0*q);
  double b0 = 1.0+al*A, b1 = -2.0*cw, b2 = 1.0-al*A;
  double a0 = 1.0+al/A, a1 = -2.0*cw, a2 = 1.0-al/A;
  PcS[k]    = (float)(b0/a0);
  PcS[6+k]  = (float)(b1/a0);
  PcS[12+k] = (float)(b2/a0);
  PcS[18+k] = (float)(a1/a0);
  PcS[24+k] = (float)(a2/a0);
}

// ---------------- fused per-channel pipeline --------------------------------
// R19 = R18 with the front-end parallelized 2x: LCHUNK 512->256.
// R18's counters showed the fused front-end costs ~193us (834 total vs 641
// verb-only) because stages 1/3 ran on 128-140 threads = 2 of 5 waves, i.e.
// 2 of 4 SIMDs issuing at 1 inst/2cyc -- issue-rate-bound, not latency.
// With 256 chunks: stage 1 runs 268 threads, stage 3 runs 256 threads (4
// waves), halving per-thread serial work and feeding all SIMDs. Stage 2's
// 12-lane scan doubles to 256 iterations (+~5us on one wave) -- net win.
// I-record indexing unchanged as a function of G (G = c*32+gg). Verb body
// verbatim R10.

__global__ __launch_bounds__(320) void k_main(const float* __restrict__ x,
                                              const float* __restrict__ p,
                                              float* __restrict__ ws,
                                              float* __restrict__ pout){
  const int LC[8] = {1116,1188,1277,1356,1422,1491,1557,1617};
  const int COFF[8] = {0,1116,2304,3581,4937,6359,7850,9407};
  const int LA[4] = {556,441,341,225};
  const int AOFF[4] = {0,556,997,1338};
  int ch = blockIdx.x, tid = threadIdx.x;
  __shared__ float cb[11024];
  __shared__ float ab[1563];
  __shared__ float cH[8][264];     // [k][8 halo + 256]
  __shared__ float xts[256];
  __shared__ float B1st[2][256];   // target staging, dbuf
  __shared__ float IldS[384];      // 32 group records x 12
  __shared__ float gB[2][32];      // group-boundary g, dbuf
  __shared__ float xfer[32];       // stage-3 outputs for samples 225..255
  // front-end scratch aliased into cb (zeroed later): 256-chunk layout
  float* Vls = cb;                 // 256*12 = 3072
  float* Zls = cb + 3072;          // 256*12 = 3072
  float* Mls = cb + 6144;          // 12*12  = 144
  float* PcS = cb + 6288;          // 40     (ends 6328 < 11024)

  float* Aio = ws + OFS_A + (size_t)ch*T;
  const float* B1c = ws + OFS_B1 + (size_t)ch*T;
  const float* IG  = ws + OFS_I + (size_t)ch*98304;
  const float* pf = p + ch*24;

  // ---------------- stage 0: params (verbatim k_params math) ----------------
  if (tid == 0){
    double gain_in = (double)pf[0]*60.0 - 48.0;
    double hp_fc   = (double)pf[1]*350.0;
    double gin = pow(10.0, gain_in/20.0);
    double K = tan(3.14159265358979323846*hp_fc/44100.0);
    double a1=(K-1.0)/(K+1.0), b0=1.0/(1.0+K);
    PcS[0]  = (float)(b0*gin);
    PcS[6]  = (float)(-b0*gin);
    PcS[12] = 0.0f;
    PcS[18] = (float)a1;
    PcS[24] = 0.0f;
  } else if (tid == 1){
    double lp_fc = (double)pf[2]*19000.0 + 3000.0;
    double K = tan(3.14159265358979323846*lp_fc/44100.0);
    double a1=(K-1.0)/(K+1.0), b0=K/(1.0+K);
    PcS[1]  = (float)b0;
    PcS[7]  = (float)b0;
    PcS[13] = 0.0f;
    PcS[19] = (float)a1;
    PcS[25] = 0.0f;
  } else if (tid == 2){
    shelf_store((double)pf[3]*14500.0 + 1500.0, (double)pf[4]*30.0 - 15.0,  1.0, PcS, 2);
  } else if (tid == 3){
    shelf_store((double)pf[5]*420.0 + 30.0,    (double)pf[6]*30.0 - 15.0, -1.0, PcS, 3);
  } else if (tid == 4){
    peak_store((double)pf[7]*6400.0 + 600.0,  (double)pf[8]*30.0 - 15.0,
               (double)pf[9]*2.5 + 0.5, PcS, 4);
  } else if (tid == 5){
    peak_store((double)pf[10]*2300.0 + 200.0, (double)pf[11]*30.0 - 15.0,
               (double)pf[12]*2.5 + 0.5, PcS, 5);
  } else if (tid == 6){
    double c_thr = (double)pf[13]*30.0 - 20.0;
    double c_rat = (double)pf[14]*19.0 + 1.0;
    double c_att = (double)pf[15]*29.0 + 1.0;
    double c_rel = (double)pf[16]*3900.0 + 100.0;
    PcS[30] = (float)c_thr;
    PcS[31] = (float)(1.0 - 1.0/c_rat);
    PcS[32] = (float)exp(-1.0/(c_att*0.001*44100.0));
    PcS[33] = (float)exp(-1.0/(c_rel*0.001*44100.0));
  } else if (tid == 7){
    double fb   = (double)pf[17]*0.28 + 0.7;
    double damp = (double)pf[18]*0.4;
    double wet1 = 3.0*(double)pf[19]*0.5*(1.0+(double)pf[21]);
    double dryg = 2.0*(double)pf[20];
    double gain_out = (double)pf[22]*60.0 - 48.0;
    double gout = pow(10.0, gain_out/20.0);
    double pan  = (double)pf[23]*0.4 + 0.3;
    PcS[34] = (float)fb;
    PcS[35] = (float)damp;
    PcS[36] = (float)(wet1*gout);
    PcS[37] = (float)(dryg*gout/0.015);
    PcS[38] = (float)cos(pan*1.57079632679489662);
    PcS[39] = (float)sin(pan*1.57079632679489662);
  } else if (tid == 8){
    float* po = pout + ch*24;
    po[0]=(float)((double)pf[0]*60.0-48.0);   po[1]=(float)((double)pf[1]*350.0);
    po[2]=(float)((double)pf[2]*19000.0+3000.0); po[3]=(float)((double)pf[3]*14500.0+1500.0);
    po[4]=(float)((double)pf[4]*30.0-15.0);   po[5]=(float)((double)pf[5]*420.0+30.0);
    po[6]=(float)((double)pf[6]*30.0-15.0);   po[7]=(float)((double)pf[7]*6400.0+600.0);
    po[8]=(float)((double)pf[8]*30.0-15.0);   po[9]=(float)((double)pf[9]*2.5+0.5);
    po[10]=(float)((double)pf[10]*2300.0+200.0); po[11]=(float)((double)pf[11]*30.0-15.0);
    po[12]=(float)((double)pf[12]*2.5+0.5);   po[13]=(float)((double)pf[13]*30.0-20.0);
    po[14]=(float)((double)pf[14]*19.0+1.0);  po[15]=(float)((double)pf[15]*29.0+1.0);
    po[16]=(float)((double)pf[16]*3900.0+100.0);
    po[17]=pf[17]; po[18]=pf[18]; po[19]=pf[19]; po[20]=pf[20]; po[21]=pf[21];
    po[22]=(float)((double)pf[22]*60.0-48.0); po[23]=(float)((double)pf[23]*0.4+0.3);
  }
  __syncthreads();

  // params to registers (all threads) + global P for k_mix
  float fb = PcS[34], damp = PcS[35], wet1 = PcS[36], dryk = PcS[37];
  float aA = PcS[32], aR = PcS[33];
  float thr = PcS[30], rt = PcS[31];
  float kA = 1.0f - aA, kR = 1.0f - aR;
  float omd = 1.0f - damp;
  float b0[6],b1[6],b2[6],a1[6],a2[6];
  if (tid < 268) load_coefs(PcS,b0,b1,b2,a1,a2);
  if (tid < 40) (ws + OFS_P + ch*64)[tid] = PcS[tid];

  // ---------------- stage 1: chunk1 (V to LDS; M task on threads 256-267) ---
  if (tid < 268){
    float z1[6]={0,0,0,0,0,0}, z2[6]={0,0,0,0,0,0};
    if (tid < CCHUNK){
      const float4* xp = (const float4*)(x + ch*T + tid*LCHUNK);
      for (int j=0;j<LCHUNK/4;j++){
        float4 v = xp[j];
        bq_step(b0,b1,b2,a1,a2,z1,z2,v.x);
        bq_step(b0,b1,b2,a1,a2,z1,z2,v.y);
        bq_step(b0,b1,b2,a1,a2,z1,z2,v.z);
        bq_step(b0,b1,b2,a1,a2,z1,z2,v.w);
      }
      #pragma unroll
      for (int k=0;k<6;k++){ Vls[tid*12+2*k]=z1[k]; Vls[tid*12+2*k+1]=z2[k]; }
    } else {
      int j = tid - CCHUNK;                  // unit state index 0..11
      if ((j & 1)==0) z1[j>>1]=1.0f; else z2[j>>1]=1.0f;
      for (int t=0;t<LCHUNK;t++) bq_step(b0,b1,b2,a1,a2,z1,z2,0.0f);
      #pragma unroll
      for (int k=0;k<6;k++){ Mls[j*12+2*k]=z1[k]; Mls[j*12+2*k+1]=z2[k]; }
    }
  }
  __syncthreads();

  // ---------------- stage 2: chunk2 scan (12-lane shfl, j-ascending) -------
  if (tid < 64){
    int i = tid; bool act = (i < 12);
    float Mr_[12];
    #pragma unroll
    for (int j=0;j<12;j++) Mr_[j] = act ? Mls[j*12+i] : 0.0f;
    float z = 0.0f;
    for (int c=0;c<CCHUNK;c++){
      if (act) Zls[c*12+i] = z;
      float zn = act ? Vls[c*12+i] : 0.0f;
      #pragma unroll
      for (int j=0;j<12;j++) zn = fmaf(Mr_[j], __shfl(z, j), zn);
      z = zn;
    }
  }
  __syncthreads();

  // ---------------- stage 3: chunk3 (A, B1, I to global) ----------------
  if (tid < CCHUNK){
    int c = tid;
    float z1[6], z2[6];
    #pragma unroll
    for (int k=0;k<6;k++){ z1[k]=Zls[c*12+2*k]; z2[k]=Zls[c*12+2*k+1]; }
    const float4* xp = (const float4*)(x + ch*T + c*LCHUNK);
    float4* Ao  = (float4*)(ws + OFS_A  + (size_t)ch*T + c*LCHUNK);
    float4* B1o = (float4*)(ws + OFS_B1 + (size_t)ch*T + c*LCHUNK);
    float*  Ig  = ws + OFS_I + (size_t)ch*98304;
    for (int gg=0; gg<LCHUNK/8; gg++){
      float4 v0 = xp[2*gg], v1 = xp[2*gg+1];
      float ya[8], Tv[8];
      ya[0]=bq_step(b0,b1,b2,a1,a2,z1,z2,v0.x);
      ya[1]=bq_step(b0,b1,b2,a1,a2,z1,z2,v0.y);
      ya[2]=bq_step(b0,b1,b2,a1,a2,z1,z2,v0.z);
      ya[3]=bq_step(b0,b1,b2,a1,a2,z1,z2,v0.w);
      ya[4]=bq_step(b0,b1,b2,a1,a2,z1,z2,v1.x);
      ya[5]=bq_step(b0,b1,b2,a1,a2,z1,z2,v1.y);
      ya[6]=bq_step(b0,b1,b2,a1,a2,z1,z2,v1.z);
      ya[7]=bq_step(b0,b1,b2,a1,a2,z1,z2,v1.w);
      #pragma unroll
      for (int s=0;s<8;s++)
        Tv[s] = fminf(0.0f, (thr - 6.0205999132796239f*log2f(fabsf(ya[s])+1e-6f))*rt);
      Ao[2*gg]   = make_float4(ya[0],ya[1],ya[2],ya[3]);
      Ao[2*gg+1] = make_float4(ya[4],ya[5],ya[6],ya[7]);
      B1o[2*gg]   = make_float4(Tv[0],Tv[1],Tv[2],Tv[3]);
      B1o[2*gg+1] = make_float4(Tv[4],Tv[5],Tv[6],Tv[7]);
      // DP: compose 8 min-affine steps
      float bb[9];
      bb[0] = kR*Tv[0]; bb[1] = kA*Tv[0];
      #pragma unroll
      for (int s=1;s<8;s++){
        float bA = kA*Tv[s], bR = kR*Tv[s];
        bb[s+1] = fmaf(aA, bb[s], bA);
        #pragma unroll
        for (int j=7;j>=1;j--){
          if (j<=s) bb[j] = fminf(fmaf(aA, bb[j-1], bA), fmaf(aR, bb[j], bR));
        }
        bb[0] = fmaf(aR, bb[0], bR);
      }
      int G = c*(LCHUNK/8) + gg;             // global group index
      float* ig = Ig + (G>>5)*384 + (G&31)*12;
      *(float4*)(ig)   = make_float4(bb[0],bb[1],bb[2],bb[3]);
      *(float4*)(ig+4) = make_float4(bb[4],bb[5],bb[6],bb[7]);
      *(float4*)(ig+8) = make_float4(bb[8],0.0f,0.0f,0.0f);
    }
  }
  __syncthreads();   // vmcnt drain: stage-3 global writes visible to verb reads

  // ---------------- verb: verbatim R10 body ----------------
  for (int i=tid;i<11024;i+=320) cb[i]=0.0f;
  for (int i=tid;i<1563;i+=320)  ab[i]=0.0f;
  for (int i=tid;i<8*264;i+=320) ((float*)cH)[i]=0.0f;
  bool scanw = (tid >= 256);
  int sl = tid - 256;
  // FIR weights damp^d
  float w[VH];
  { float pw = 1.0f;
    #pragma unroll
    for (int d=0;d<VH;d++){ w[d]=pw; pw*=damp; } }
  // scan slopes s_j = aA^j aR^(8-j)
  float sj[9];
  { float pA = 1.0f;
    #pragma unroll
    for (int j=0;j<9;j++){ sj[j]=pA; pA*=aA; }
    float pR = 1.0f;
    #pragma unroll
    for (int j=8;j>=0;j--){ sj[j]*=pR; pR*=aR; } }
  int cbb[8] = {0,0,0,0,0,0,0,0};
  int abb[4] = {0,0,0,0};
  float gcarry = 0.0f;
  float4 iR0, iR1, bR;
  float xv = 0.0f;

  // ---- prologue: IldS=I(0); B1st[0]=t(0), B1st[1]=t(1); regs=I(1); xv=x(0) ----
  if (scanw){
    const float4* isrc = (const float4*)(IG);
    float4* idst = (float4*)IldS;
    idst[sl] = isrc[sl];
    if (sl < 32) idst[64+sl] = isrc[64+sl];
    iR0 = isrc[96+sl];
    if (sl < 32) iR1 = isrc[96+64+sl];
    const float4* bsrc = (const float4*)(B1c);
    ((float4*)B1st[0])[sl] = bsrc[sl];
    ((float4*)B1st[1])[sl] = bsrc[64+sl];
  }
  if (tid < 256) xv = Aio[tid];
  __syncthreads();
  if (tid == 256){
    float g = 0.0f;
    for (int m=0;m<32;m++){
      gB[0][m] = g;
      const float* Ip = &IldS[m*12];
      float f0=fmaf(sj[0],g,Ip[0]), f1=fmaf(sj[1],g,Ip[1]), f2=fmaf(sj[2],g,Ip[2]);
      float f3=fmaf(sj[3],g,Ip[3]), f4=fmaf(sj[4],g,Ip[4]), f5=fmaf(sj[5],g,Ip[5]);
      float f6=fmaf(sj[6],g,Ip[6]), f7=fmaf(sj[7],g,Ip[7]), f8=fmaf(sj[8],g,Ip[8]);
      g = fminf(fminf(fminf(f0,f1),fminf(f2,f3)),
                fminf(fminf(f4,f5),fminf(fminf(f6,f7),f8)));
    }
    gcarry = g;
  }
  __syncthreads();

  for (int i=0;i<NBLK;i++){
    int t0 = i<<8;
    int p2 = i & 1;
    float xt = 0.0f, acc = 0.0f, a = 0.0f;
    // ---------- phase A (LDS-only) ----------
    if (tid < 256){
      int m = tid>>3, r = tid&7;
      float g = gB[p2][m];
      const float* Bl = B1st[p2] + (m<<3);
      float4 q0 = *(const float4*)(Bl);
      float4 q1 = *(const float4*)(Bl+4);
      float tv[8] = {q0.x,q0.y,q0.z,q0.w,q1.x,q1.y,q1.z,q1.w};
      #pragma unroll
      for (int s=0;s<8;s++){
        if (s<=r){
          float tt = tv[s];
          g = fminf(fmaf(aA,g,kA*tt), fmaf(aR,g,kR*tt));
        }
      }
      xt = xv * exp2f(g*0.16609640474436813f) * 0.015f;
      xts[tid] = xt;
      #pragma unroll
      for (int k=0;k<8;k++){
        int idx = cbb[k]+tid; if (idx>=LC[k]) idx-=LC[k];
        float o = cb[COFF[k]+idx];
        cH[k][VH+tid] = omd*o;
        acc += o;
      }
    } else if (i+1 < NBLK){
      // wave4: LDS-write staged regs: IldS = I(i+1); B1st[(i+1)&1] = t(i+1)
      float4* idst = (float4*)IldS;
      idst[sl] = iR0;
      if (sl < 32) idst[64+sl] = iR1;
      if (i >= 1) ((float4*)B1st[(i+1)&1])[sl] = bR;
    }
    __syncthreads();
    // ---------- phase B1: issue globals first, then compute ----------
    if (tid < 256){
      if (i+1 < NBLK) xv = Aio[t0+256+tid];    // prefetch next x (drain covered)
      // FIR damping + comb writes
      #pragma unroll
      for (int k=0;k<8;k++){
        float s = 0.0f;
        #pragma unroll
        for (int d=0;d<VH;d++) s = fmaf(w[d], cH[k][VH+tid-d], s);
        int idx = cbb[k]+tid; if (idx>=LC[k]) idx-=LC[k];
        cb[COFF[k]+idx] = fmaf(fb, s, xt);
      }
      // allpass stages 1-3, per-lane registers (slots unique: SB <= L)
      a = acc;
      #pragma unroll
      for (int j=0;j<3;j++){
        int idx = abb[j]+tid; if (idx>=LA[j]) idx-=LA[j];
        float bv = ab[AOFF[j]+idx];
        ab[AOFF[j]+idx] = fmaf(0.5f, bv, a);
        a = bv - a;
      }
      if (tid >= 225) xfer[tid-225] = a;
    } else {
      if (i+2 < NBLK){                         // stage block i+2 into regs
        const float4* isrc = (const float4*)(IG + (size_t)(i+2)*384);
        iR0 = isrc[sl];
        if (sl < 32) iR1 = isrc[64+sl];
        const float4* bsrc = (const float4*)(B1c + (size_t)(i+2)*SB);
        bR = bsrc[sl];
      }
      if (tid == 256 && i+1 < NBLK){           // scan block i+1
        int q = (i+1)&1;
        float g = gcarry;
        #pragma unroll 4
        for (int m=0;m<32;m++){
          gB[q][m] = g;
          const float* Ip = &IldS[m*12];
          float f0=fmaf(sj[0],g,Ip[0]), f1=fmaf(sj[1],g,Ip[1]), f2=fmaf(sj[2],g,Ip[2]);
          float f3=fmaf(sj[3],g,Ip[3]), f4=fmaf(sj[4],g,Ip[4]), f5=fmaf(sj[5],g,Ip[5]);
          float f6=fmaf(sj[6],g,Ip[6]), f7=fmaf(sj[7],g,Ip[7]), f8=fmaf(sj[8],g,Ip[8]);
          g = fminf(fminf(fminf(f0,f1),fminf(f2,f3)),
                    fminf(fminf(f4,f5),fminf(fminf(f6,f7),f8)));
        }
        gcarry = g;
      }
    }
    __syncthreads();
    // ---------- phase B2: allpass stage 4 (L=225) + output ----------
    if (tid < 225){
      int idx = abb[3]+tid; if (idx>=225) idx-=225;
      float bv = ab[AOFF[3]+idx];
      float b  = fmaf(0.5f, bv, a);
      float y  = bv - a;
      Aio[t0+tid] = fmaf(y, wet1, xts[tid]*dryk);
      if (tid < 31){
        float a2v = xfer[tid];             // sample tid+225
        float y2 = b - a2v;
        ab[AOFF[3]+idx] = fmaf(0.5f, b, a2v);
        Aio[t0+225+tid] = fmaf(y2, wet1, xts[225+tid]*dryk);
      } else {
        ab[AOFF[3]+idx] = b;
      }
    } else if (tid >= 232 && tid < 288){
      int q = tid-232; int k = q/7, d = q%7;   // halo: prev block samples 249..255
      cH[k][1+d] = cH[k][257+d];
    }
    #pragma unroll
    for (int k=0;k<8;k++){ cbb[k]+=SB; if (cbb[k]>=LC[k]) cbb[k]-=LC[k]; }
    #pragma unroll
    for (int j=0;j<4;j++){
      abb[j]+=SB;
      if (abb[j]>=LA[j]) abb[j]-=LA[j];
      if (abb[j]>=LA[j]) abb[j]-=LA[j];   // L=225 < SB=256 needs 2nd wrap
    }
    __syncthreads();
  }
}

// ---------------- pan mix ----------------

__global__ void k_mix(const float* __restrict__ ws, float* __restrict__ out){
  int id = blockIdx.x*256 + threadIdx.x;   // 4*65536
  int t = id & (T-1), b = id >> 16;
  const float* Av = ws + OFS_A + (size_t)b*8*T + t;
  const float* P = ws + OFS_P;
  float s0=0.0f, s1=0.0f;
  #pragma unroll
  for (int n=0;n<8;n++){
    float v = Av[(size_t)n*T];
    int ch = b*8+n;
    s0 = fmaf(v, P[ch*64+38], s0);
    s1 = fmaf(v, P[ch*64+39], s1);
  }
  out[b*2*T + t]     = s0;
  out[b*2*T + T + t] = s1;
}

extern "C" void kernel_launch(void* const* d_in, const int* in_sizes, int n_in,
                              void* d_out, int out_size, void* d_ws, size_t ws_size,
                              hipStream_t stream) {
  const float* x = (const float*)d_in[0];
  const float* p = (const float*)d_in[1];
  float* out = (float*)d_out;
  float* ws  = (float*)d_ws;

  k_main<<<NCH, 320, 0, stream>>>(x, p, ws, out + 4*2*T);
  k_mix <<<(4*T)/256, 256, 0, stream>>>(ws, out);
}